// Round 3
// baseline (861.630 us; speedup 1.0000x reference)
//
#include <hip/hip_runtime.h>
#include <math.h>

#define BB 16
#define AA 128
#define NNB 127
#define FF 128
#define GG 25

__device__ __forceinline__ float ssp_f(float x) {
    // softplus(x) - log(2), numerically stable
    return fmaxf(x, 0.f) + log1pf(__expf(-fabsf(x))) - 0.6931471805599453f;
}

// ---- x init: x[b,a,f] = embeddings[Z[b,a], f] ----
__global__ __launch_bounds__(256) void k_init_x(const float* __restrict__ emb,
                                                const int* __restrict__ z,
                                                float* __restrict__ x) {
    int i = blockIdx.x * 256 + threadIdx.x;
    if (i < BB * AA * FF) {
        int row = i >> 7;       // /F
        int f = i & 127;
        x[i] = emb[z[row] * FF + f];
    }
}

// ---- y = x @ W (no bias), one block per row ----
__global__ __launch_bounds__(128) void k_y(const float* __restrict__ x,
                                           const float* __restrict__ W,
                                           float* __restrict__ y) {
    int row = blockIdx.x;
    int t = threadIdx.x;
    __shared__ float xs[FF];
    xs[t] = x[row * FF + t];
    __syncthreads();
    float acc = 0.f;
#pragma unroll 8
    for (int k = 0; k < FF; ++k) acc += xs[k] * W[k * FF + t];
    y[row * FF + t] = acc;
}

// ---- out: v = ssp(agg@Wf + bf) @ Wd + bd ; x += v ; optionally write d_out ----
__global__ __launch_bounds__(128) void k_out(const float* __restrict__ agg,
                                             const float* __restrict__ Wf,
                                             const float* __restrict__ bf,
                                             const float* __restrict__ Wd,
                                             const float* __restrict__ bd,
                                             float* __restrict__ x,
                                             float* __restrict__ out,
                                             int write_out) {
    int row = blockIdx.x;
    int t = threadIdx.x;
    __shared__ float as_[FF];
    __shared__ float ts[FF];
    as_[t] = agg[row * FF + t];
    __syncthreads();
    float acc = bf[t];
#pragma unroll 8
    for (int k = 0; k < FF; ++k) acc += as_[k] * Wf[k * FF + t];
    ts[t] = ssp_f(acc);
    __syncthreads();
    float acc2 = bd[t];
#pragma unroll 8
    for (int k = 0; k < FF; ++k) acc2 += ts[k] * Wd[k * FF + t];
    float xn = x[row * FF + t] + acc2;
    x[row * FF + t] = xn;
    if (write_out) out[row * FF + t] = xn;
}

// ---- fused cfconv: one block per (b,a) atom ----
// phase0: distances r, CM = CosineCutoff*mask, gaussians fij -> LDS
// phase1: h = ssp(fij @ W1 + b1) -> LDS [128 rows x 129 stride]
// phase2: per (n,f): Wfilt = (h@W2 + b2)*CM ; agg[f] += y[nbr[n]][f]*Wfilt
__global__ __launch_bounds__(256, 2) void k_cfconv(
    const float* __restrict__ positions, const float* __restrict__ cell,
    const float* __restrict__ cell_offset, const float* __restrict__ nmask,
    const int* __restrict__ neighbors,
    const float* __restrict__ W1, const float* __restrict__ b1,
    const float* __restrict__ W2, const float* __restrict__ b2,
    const float* __restrict__ y, float* __restrict__ agg) {
    const int row = blockIdx.x;      // b*A + a
    const int b = row >> 7;          // / AA
    const int t = threadIdx.x;

    __shared__ float h_lds[128 * 129];   // 66048 B
    __shared__ float scratch[3200];      // fij [127*25]; later: w2t[0..2047] + agg_red[2048..3071]
    __shared__ float r_lds[NNB];
    __shared__ float cm_lds[NNB];
    __shared__ int nbr_lds[NNB];

    // ---- phase 0a: distances + cutoff ----
    if (t < NNB) {
        int nb = neighbors[row * NNB + t];
        nbr_lds[t] = nb;
        float px = positions[row * 3 + 0];
        float py = positions[row * 3 + 1];
        float pz = positions[row * 3 + 2];
        int nrow = b * AA + nb;
        float qx = positions[nrow * 3 + 0];
        float qy = positions[nrow * 3 + 1];
        float qz = positions[nrow * 3 + 2];
        const float* co = cell_offset + (size_t)row * NNB * 3 + (size_t)t * 3;
        const float* cl = cell + b * 9;
        float c0 = co[0], c1 = co[1], c2 = co[2];
        float ox = c0 * cl[0] + c1 * cl[3] + c2 * cl[6];
        float oy = c0 * cl[1] + c1 * cl[4] + c2 * cl[7];
        float oz = c0 * cl[2] + c1 * cl[5] + c2 * cl[8];
        float dx = qx - px + ox;
        float dy = qy - py + oy;
        float dz = qz - pz + oz;
        float d2 = dx * dx + dy * dy + dz * dz;
        float mk = nmask[row * NNB + t];
        float r = (mk > 0.f) ? sqrtf(d2) : 0.f;
        r_lds[t] = r;
        float Cc = 0.5f * (cosf(r * (3.14159265358979323846f / 5.0f)) + 1.f);
        Cc = (r < 5.0f) ? Cc : 0.f;
        cm_lds[t] = Cc * mk;
    }
    __syncthreads();

    // ---- phase 0b: gaussian smearing into scratch (fij[n][g]) ----
    const float width = 5.0f / (GG - 1);
    const float coeff = -0.5f / (width * width);
    for (int idx = t; idx < NNB * GG; idx += 256) {
        int n = idx / GG;
        int g = idx - n * GG;
        float diff = r_lds[n] - g * width;
        scratch[idx] = __expf(coeff * diff * diff);
    }
    __syncthreads();

    // ---- phase 1: h = ssp(fij @ W1 + b1) ----
    {
        const int f1 = t & 127;
        const int nh = t >> 7;
        const float b1f = b1[f1];
        for (int n = nh; n < NNB; n += 2) {
            float acc = b1f;
            const float* fr = &scratch[n * GG];
#pragma unroll
            for (int g = 0; g < GG; ++g) acc += fr[g] * W1[g * FF + f1];
            h_lds[n * 129 + f1] = ssp_f(acc);
        }
    }
    __syncthreads();

    // ---- phase 2: register-tiled [127x128] x [128x128] with LDS-staged W2 tiles ----
    const int tx = t & 31;   // f-quad group
    const int ty = t >> 5;   // n-group 0..7
    const int f0 = tx * 4;

    float acc[16][4];
#pragma unroll
    for (int i = 0; i < 16; ++i) {
#pragma unroll
        for (int j = 0; j < 4; ++j) acc[i][j] = 0.f;
    }

    float4* w2t4 = (float4*)scratch;  // tile [16][128] floats = [16][32] float4
    for (int k0 = 0; k0 < FF; k0 += 16) {
        __syncthreads();  // previous readers of scratch done
        const float4* src = (const float4*)(W2 + (size_t)k0 * FF);
        for (int id = t; id < 16 * FF / 4; id += 256) w2t4[id] = src[id];
        __syncthreads();
#pragma unroll 4
        for (int kk = 0; kk < 16; ++kk) {
            float4 w = w2t4[kk * 32 + tx];
            const int hb = k0 + kk;
#pragma unroll
            for (int i = 0; i < 16; ++i) {
                float hv = h_lds[(ty + 8 * i) * 129 + hb];
                acc[i][0] += hv * w.x;
                acc[i][1] += hv * w.y;
                acc[i][2] += hv * w.z;
                acc[i][3] += hv * w.w;
            }
        }
    }

    // ---- epilogue: Wfilt = (acc + b2)*CM ; agg_local += y_nbh * Wfilt ----
    float aggl[4] = {0.f, 0.f, 0.f, 0.f};
    const float4 b2v = *(const float4*)(b2 + f0);
    const int bA = b * AA;
#pragma unroll
    for (int i = 0; i < 16; ++i) {
        int n = ty + 8 * i;
        if (n < NNB) {
            float cm = cm_lds[n];
            int nb = nbr_lds[n];
            const float4 yv = *(const float4*)(y + ((size_t)(bA + nb)) * FF + f0);
            aggl[0] += yv.x * (acc[i][0] + b2v.x) * cm;
            aggl[1] += yv.y * (acc[i][1] + b2v.y) * cm;
            aggl[2] += yv.z * (acc[i][2] + b2v.z) * cm;
            aggl[3] += yv.w * (acc[i][3] + b2v.w) * cm;
        }
    }
    __syncthreads();  // w2t reads done (loop ended with compute); safe before re-reading scratch[2048..]
    float4* aggred4 = (float4*)(scratch + 2048);
    aggred4[ty * 32 + tx] = make_float4(aggl[0], aggl[1], aggl[2], aggl[3]);
    __syncthreads();
    if (t < FF) {
        float s = 0.f;
#pragma unroll
        for (int g8 = 0; g8 < 8; ++g8) s += scratch[2048 + g8 * 128 + t];
        agg[(size_t)row * FF + t] = s;
    }
}

extern "C" void kernel_launch(void* const* d_in, const int* in_sizes, int n_in,
                              void* d_out, int out_size, void* d_ws, size_t ws_size,
                              hipStream_t stream) {
    const float* positions   = (const float*)d_in[0];
    const float* cell        = (const float*)d_in[1];
    const float* cell_offset = (const float*)d_in[2];
    const float* nmask       = (const float*)d_in[3];
    const float* emb         = (const float*)d_in[4];
    const float* filt_W1     = (const float*)d_in[5];
    const float* filt_b1     = (const float*)d_in[6];
    const float* filt_W2     = (const float*)d_in[7];
    const float* filt_b2     = (const float*)d_in[8];
    const float* in2f_W      = (const float*)d_in[9];
    const float* f2out_W     = (const float*)d_in[10];
    const float* f2out_b     = (const float*)d_in[11];
    const float* dense_W     = (const float*)d_in[12];
    const float* dense_b     = (const float*)d_in[13];
    const int* atomic_numbers = (const int*)d_in[14];
    const int* neighbors      = (const int*)d_in[15];
    float* out = (float*)d_out;

    float* x   = (float*)d_ws;            // B*A*F
    float* yb  = x + BB * AA * FF;        // B*A*F
    float* agg = yb + BB * AA * FF;       // B*A*F

    k_init_x<<<(BB * AA * FF + 255) / 256, 256, 0, stream>>>(emb, atomic_numbers, x);
    for (int l = 0; l < 3; ++l) {
        k_y<<<BB * AA, FF, 0, stream>>>(x, in2f_W + (size_t)l * FF * FF, yb);
        k_cfconv<<<BB * AA, 256, 0, stream>>>(positions, cell, cell_offset, nmask, neighbors,
                                              filt_W1 + (size_t)l * GG * FF, filt_b1 + (size_t)l * FF,
                                              filt_W2 + (size_t)l * FF * FF, filt_b2 + (size_t)l * FF,
                                              yb, agg);
        k_out<<<BB * AA, FF, 0, stream>>>(agg, f2out_W + (size_t)l * FF * FF, f2out_b + (size_t)l * FF,
                                          dense_W + (size_t)l * FF * FF, dense_b + (size_t)l * FF,
                                          x, out, (l == 2) ? 1 : 0);
    }
}

// Round 4
// 436.099 us; speedup vs baseline: 1.9758x; 1.9758x over previous
//
#include <hip/hip_runtime.h>
#include <math.h>

#define BB 16
#define AA 128
#define NNB 127
#define FF 128
#define GG 25

typedef __attribute__((ext_vector_type(8))) short bf16x8;
typedef __attribute__((ext_vector_type(4))) float f32x4;
typedef unsigned short ushort_t;

__device__ __forceinline__ float ssp_f(float x) {
    return fmaxf(x, 0.f) + log1pf(__expf(-fabsf(x))) - 0.6931471805599453f;
}

__device__ __forceinline__ ushort_t f2bf(float f) {
    unsigned int u = __float_as_uint(f);
    unsigned int r = (u + 0x7fffu + ((u >> 16) & 1u)) >> 16;
    return (ushort_t)r;
}

// ---- prep: W1 -> W1T bf16 [3][128f][32g(pad0)]; W2 -> pre-swizzled W2T bf16 LDS image ----
__global__ __launch_bounds__(256) void k_prep(const float* __restrict__ W1,
                                              const float* __restrict__ W2,
                                              ushort_t* __restrict__ w1t,
                                              ushort_t* __restrict__ w2s) {
    int i = blockIdx.x * 256 + threadIdx.x;
    if (i < 3 * 128 * 32) {
        int l = i >> 12, rem = i & 4095, f = rem >> 5, g = rem & 31;
        float v = (g < GG) ? W1[l * GG * FF + g * FF + f] : 0.f;
        w1t[i] = f2bf(v);
    }
    if (i < 3 * 16384) {
        int l = i >> 14, rem = i & 16383, f = rem >> 7, k = rem & 127;
        // store so a LINEAR LDS copy yields the XOR-swizzled layout (read applies same XOR)
        w2s[l * 16384 + f * 128 + (k ^ ((f & 7) << 3))] = f2bf(W2[l * 16384 + k * FF + f]);
    }
}

// ---- x init ----
__global__ __launch_bounds__(256) void k_init_x(const float* __restrict__ emb,
                                                const int* __restrict__ z,
                                                float* __restrict__ x) {
    int i = blockIdx.x * 256 + threadIdx.x;
    if (i < BB * AA * FF) {
        int row = i >> 7, f = i & 127;
        x[i] = emb[z[row] * FF + f];
    }
}

// ---- y = x @ W ----
__global__ __launch_bounds__(128) void k_y(const float* __restrict__ x,
                                           const float* __restrict__ W,
                                           float* __restrict__ y) {
    int row = blockIdx.x, t = threadIdx.x;
    __shared__ float xs[FF];
    xs[t] = x[row * FF + t];
    __syncthreads();
    float acc = 0.f;
#pragma unroll 8
    for (int k = 0; k < FF; ++k) acc += xs[k] * W[k * FF + t];
    y[row * FF + t] = acc;
}

// ---- out block ----
__global__ __launch_bounds__(128) void k_out(const float* __restrict__ agg,
                                             const float* __restrict__ Wf,
                                             const float* __restrict__ bf,
                                             const float* __restrict__ Wd,
                                             const float* __restrict__ bd,
                                             float* __restrict__ x,
                                             float* __restrict__ out,
                                             int write_out) {
    int row = blockIdx.x, t = threadIdx.x;
    __shared__ float as_[FF];
    __shared__ float ts[FF];
    as_[t] = agg[row * FF + t];
    __syncthreads();
    float acc = bf[t];
#pragma unroll 8
    for (int k = 0; k < FF; ++k) acc += as_[k] * Wf[k * FF + t];
    ts[t] = ssp_f(acc);
    __syncthreads();
    float acc2 = bd[t];
#pragma unroll 8
    for (int k = 0; k < FF; ++k) acc2 += ts[k] * Wd[k * FF + t];
    float xn = x[row * FF + t] + acc2;
    x[row * FF + t] = xn;
    if (write_out) out[row * FF + t] = xn;
}

// LDS layout (dynamic, 76768 B):
//  [0,32768)      h bf16 [128n][128k], XOR-swizzled: byte ^= (n&7)<<4
//  [32768,65536)  W2T bf16 (linear copy of pre-swizzled global image)
//  [0,67040)      (epilogue alias) y fp32 [127][132]
//  [0,8192)       (final alias) reduction scratch 2048 f32
//  [67040,75232)  fij bf16 [128n][32g]
//  [75232,75744)  cm f32[128]; [75744,76256) nbr i32[128]; [76256,76768) r f32[128]
#define SMEM_BYTES 76768

__global__ __launch_bounds__(256, 2) void k_cfconv(
    const float* __restrict__ positions, const float* __restrict__ cell,
    const float* __restrict__ cell_offset, const float* __restrict__ nmask,
    const int* __restrict__ neighbors,
    const ushort_t* __restrict__ w1t, const float* __restrict__ b1,
    const ushort_t* __restrict__ w2s, const float* __restrict__ b2,
    const float* __restrict__ y, float* __restrict__ agg) {
    extern __shared__ char smem[];
    ushort_t* fij_s = (ushort_t*)(smem + 67040);
    float* cm_s = (float*)(smem + 75232);
    int* nbr_s = (int*)(smem + 75744);
    float* r_s = (float*)(smem + 76256);
    float* y_s = (float*)smem;
    float* red_s = (float*)smem;

    const int row = blockIdx.x;
    const int b = row >> 7;
    const int t = threadIdx.x;
    const int lane = t & 63, w = t >> 6;
    const int l15 = lane & 15, l4 = lane >> 4;

    // -- issue W2T global loads early (held in regs until LDS write) --
    uint4 wreg[8];
    {
        const uint4* wsrc = (const uint4*)w2s;
#pragma unroll
        for (int i = 0; i < 8; ++i) wreg[i] = wsrc[t + (i << 8)];
    }

    // -- phase 0a: distances + cutoff --
    if (t < NNB) {
        int nb = neighbors[row * NNB + t];
        nbr_s[t] = nb;
        float px = positions[row * 3 + 0], py = positions[row * 3 + 1], pz = positions[row * 3 + 2];
        int nrow = b * AA + nb;
        float qx = positions[nrow * 3 + 0], qy = positions[nrow * 3 + 1], qz = positions[nrow * 3 + 2];
        const float* co = cell_offset + (size_t)row * NNB * 3 + (size_t)t * 3;
        const float* cl = cell + b * 9;
        float c0 = co[0], c1 = co[1], c2 = co[2];
        float ox = c0 * cl[0] + c1 * cl[3] + c2 * cl[6];
        float oy = c0 * cl[1] + c1 * cl[4] + c2 * cl[7];
        float oz = c0 * cl[2] + c1 * cl[5] + c2 * cl[8];
        float dx = qx - px + ox, dy = qy - py + oy, dz = qz - pz + oz;
        float d2 = dx * dx + dy * dy + dz * dz;
        float mk = nmask[row * NNB + t];
        float r = (mk > 0.f) ? sqrtf(d2) : 0.f;
        r_s[t] = r;
        float Cc = 0.5f * (cosf(r * (3.14159265358979323846f / 5.0f)) + 1.f);
        Cc = (r < 5.0f) ? Cc : 0.f;
        cm_s[t] = Cc * mk;
    } else if (t == NNB) {
        cm_s[NNB] = 0.f; nbr_s[NNB] = 0; r_s[NNB] = 1e9f;
    }
    __syncthreads();   // r_s ready

    // -- phase 0b: fij bf16 [128][32] (row 127 and g>=25 zero) --
    {
        const float width = 5.0f / (GG - 1);
        const float coeff = -0.5f / (width * width);
#pragma unroll
        for (int ii = 0; ii < 16; ++ii) {
            int idx = t + ii * 256;
            int n = idx >> 5, g = idx & 31;
            float v = 0.f;
            if (n < NNB && g < GG) {
                float diff = r_s[n] - g * width;
                v = __expf(coeff * diff * diff);
            }
            fij_s[idx] = f2bf(v);
        }
    }
    // -- write W2T tile to LDS --
    {
        uint4* wdst = (uint4*)(smem + 32768);
#pragma unroll
        for (int i = 0; i < 8; ++i) wdst[t + (i << 8)] = wreg[i];
    }
    __syncthreads();   // fij + W2T ready

    // -- phase 1: h = ssp(fij @ W1 + b1) via MFMA, write bf16 swizzled --
    {
        bf16x8 fa[2];
#pragma unroll
        for (int mi = 0; mi < 2; ++mi) {
            int n = (w << 5) + (mi << 4) + l15;
            fa[mi] = *(const bf16x8*)((const char*)fij_s + n * 64 + (l4 << 4));
        }
#pragma unroll
        for (int ft = 0; ft < 8; ++ft) {
            int f = (ft << 4) + l15;
            bf16x8 bw = *(const bf16x8*)(w1t + f * 32 + (l4 << 3));
            float b1v = b1[f];
            f32x4 c0 = {b1v, b1v, b1v, b1v};
#pragma unroll
            for (int mi = 0; mi < 2; ++mi) {
                f32x4 d = __builtin_amdgcn_mfma_f32_16x16x32_bf16(fa[mi], bw, c0, 0, 0, 0);
#pragma unroll
                for (int r = 0; r < 4; ++r) {
                    int n = (w << 5) + (mi << 4) + (l4 << 2) + r;
                    int byte = n * 256 + ((f << 1) ^ ((n & 7) << 4));
                    *(ushort_t*)(smem + byte) = f2bf(ssp_f(d[r]));
                }
            }
        }
    }
    __syncthreads();   // h ready

    // -- phase 2: Wfilt = h @ W2 + b2 via MFMA (acc init = b2) --
    f32x4 acc[2][8];
#pragma unroll
    for (int ft = 0; ft < 8; ++ft) {
        float b2v = b2[(ft << 4) + l15];
        f32x4 c0 = {b2v, b2v, b2v, b2v};
        acc[0][ft] = c0;
        acc[1][ft] = c0;
    }
#pragma unroll
    for (int ks = 0; ks < 4; ++ks) {
        bf16x8 ha[2];
#pragma unroll
        for (int mi = 0; mi < 2; ++mi) {
            int n = (w << 5) + (mi << 4) + l15;
            int byte = n * 256 + ((((ks << 2) + l4) << 4) ^ ((n & 7) << 4));
            ha[mi] = *(const bf16x8*)(smem + byte);
        }
#pragma unroll
        for (int ft = 0; ft < 8; ++ft) {
            int f = (ft << 4) + l15;
            int byte = 32768 + f * 256 + ((((ks << 2) + l4) << 4) ^ ((f & 7) << 4));
            bf16x8 wb = *(const bf16x8*)(smem + byte);
            acc[0][ft] = __builtin_amdgcn_mfma_f32_16x16x32_bf16(ha[0], wb, acc[0][ft], 0, 0, 0);
            acc[1][ft] = __builtin_amdgcn_mfma_f32_16x16x32_bf16(ha[1], wb, acc[1][ft], 0, 0, 0);
        }
    }
    __syncthreads();   // all GEMM LDS reads done

    // -- stage y_nbh rows into LDS (fp32, stride 132) --
    {
        const int bA = b * AA;
        float4* yd4 = (float4*)smem;
        const float4* ysrc = (const float4*)y;
        for (int idx = t; idx < NNB * 32; idx += 256) {
            int n = idx >> 5, c = idx & 31;
            yd4[n * 33 + c] = ysrc[((size_t)(bA + nbr_s[n]) << 5) + c];
        }
    }
    __syncthreads();   // y_s ready

    // -- epilogue: part[f] += y * (acc * cm) --
    float part[8];
#pragma unroll
    for (int ft = 0; ft < 8; ++ft) part[ft] = 0.f;
#pragma unroll
    for (int mi = 0; mi < 2; ++mi) {
#pragma unroll
        for (int r = 0; r < 4; ++r) {
            int n = (w << 5) + (mi << 4) + (l4 << 2) + r;
            if (n < NNB) {
                float cmv = cm_s[n];
                const float* yrow = y_s + n * 132;
#pragma unroll
                for (int ft = 0; ft < 8; ++ft)
                    part[ft] = fmaf(yrow[(ft << 4) + l15], acc[mi][ft][r] * cmv, part[ft]);
            }
        }
    }
    __syncthreads();   // y reads done; safe to overwrite with red
#pragma unroll
    for (int ft = 0; ft < 8; ++ft)
        red_s[((w << 2) + l4) * 128 + (ft << 4) + l15] = part[ft];
    __syncthreads();
    if (t < FF) {
        float s = 0.f;
#pragma unroll
        for (int g = 0; g < 16; ++g) s += red_s[g * 128 + t];
        agg[(size_t)row * FF + t] = s;
    }
}

extern "C" void kernel_launch(void* const* d_in, const int* in_sizes, int n_in,
                              void* d_out, int out_size, void* d_ws, size_t ws_size,
                              hipStream_t stream) {
    const float* positions   = (const float*)d_in[0];
    const float* cell        = (const float*)d_in[1];
    const float* cell_offset = (const float*)d_in[2];
    const float* nmask       = (const float*)d_in[3];
    const float* emb         = (const float*)d_in[4];
    const float* filt_W1     = (const float*)d_in[5];
    const float* filt_b1     = (const float*)d_in[6];
    const float* filt_W2     = (const float*)d_in[7];
    const float* filt_b2     = (const float*)d_in[8];
    const float* in2f_W      = (const float*)d_in[9];
    const float* f2out_W     = (const float*)d_in[10];
    const float* f2out_b     = (const float*)d_in[11];
    const float* dense_W     = (const float*)d_in[12];
    const float* dense_b     = (const float*)d_in[13];
    const int* atomic_numbers = (const int*)d_in[14];
    const int* neighbors      = (const int*)d_in[15];
    float* out = (float*)d_out;

    float* x   = (float*)d_ws;
    float* yb  = x + BB * AA * FF;
    float* agg = yb + BB * AA * FF;
    ushort_t* w1t = (ushort_t*)(agg + BB * AA * FF);   // 3*128*32
    ushort_t* w2s = w1t + 3 * 128 * 32;                // 3*128*128

    k_prep<<<192, 256, 0, stream>>>(filt_W1, filt_W2, w1t, w2s);
    k_init_x<<<(BB * AA * FF + 255) / 256, 256, 0, stream>>>(emb, atomic_numbers, x);
    for (int l = 0; l < 3; ++l) {
        k_y<<<BB * AA, FF, 0, stream>>>(x, in2f_W + (size_t)l * FF * FF, yb);
        k_cfconv<<<BB * AA, 256, SMEM_BYTES, stream>>>(
            positions, cell, cell_offset, nmask, neighbors,
            w1t + (size_t)l * 128 * 32, filt_b1 + (size_t)l * FF,
            w2s + (size_t)l * 128 * 128, filt_b2 + (size_t)l * FF,
            yb, agg);
        k_out<<<BB * AA, FF, 0, stream>>>(agg, f2out_W + (size_t)l * FF * FF, f2out_b + (size_t)l * FF,
                                          dense_W + (size_t)l * FF * FF, dense_b + (size_t)l * FF,
                                          x, out, (l == 2) ? 1 : 0);
    }
}

// Round 5
// 256.844 us; speedup vs baseline: 3.3547x; 1.6979x over previous
//
#include <hip/hip_runtime.h>
#include <math.h>

#define BB 16
#define AA 128
#define NNB 127
#define FF 128
#define GG 25

typedef __attribute__((ext_vector_type(8))) short bf16x8;
typedef __attribute__((ext_vector_type(4))) float f32x4;
typedef unsigned short ushort_t;

__device__ __forceinline__ float ssp_f(float x) {
    // precise (used in tiny k_out only)
    return fmaxf(x, 0.f) + log1pf(__expf(-fabsf(x))) - 0.6931471805599453f;
}

__device__ __forceinline__ float ssp_fast(float x) {
    // softplus(x)-log2 via native exp2/log2 pipes (~8 ops)
    float e = __expf(-fabsf(x));
    return fmaxf(x, 0.f) + __logf(1.f + e) - 0.6931471805599453f;
}

__device__ __forceinline__ ushort_t f2bf(float f) {
    unsigned int u = __float_as_uint(f);
    unsigned int r = (u + 0x7fffu + ((u >> 16) & 1u)) >> 16;
    return (ushort_t)r;
}

__device__ __forceinline__ unsigned int pack2bf(float lo, float hi) {
    return (unsigned int)f2bf(lo) | ((unsigned int)f2bf(hi) << 16);
}

// ---- prep: W1 -> W1T bf16 [3][128f][32g(pad0)]; W2 -> pre-swizzled W2T bf16 LDS image ----
__global__ __launch_bounds__(256) void k_prep(const float* __restrict__ W1,
                                              const float* __restrict__ W2,
                                              ushort_t* __restrict__ w1t,
                                              ushort_t* __restrict__ w2s) {
    int i = blockIdx.x * 256 + threadIdx.x;
    if (i < 3 * 128 * 32) {
        int l = i >> 12, rem = i & 4095, f = rem >> 5, g = rem & 31;
        float v = (g < GG) ? W1[l * GG * FF + g * FF + f] : 0.f;
        w1t[i] = f2bf(v);
    }
    if (i < 3 * 16384) {
        int l = i >> 14, rem = i & 16383, f = rem >> 7, k = rem & 127;
        // store so a LINEAR LDS copy yields the XOR-swizzled layout (read applies same XOR)
        w2s[l * 16384 + f * 128 + (k ^ ((f & 7) << 3))] = f2bf(W2[l * 16384 + k * FF + f]);
    }
}

// ---- x init ----
__global__ __launch_bounds__(256) void k_init_x(const float* __restrict__ emb,
                                                const int* __restrict__ z,
                                                float* __restrict__ x) {
    int i = blockIdx.x * 256 + threadIdx.x;
    if (i < BB * AA * FF) {
        int row = i >> 7, f = i & 127;
        x[i] = emb[z[row] * FF + f];
    }
}

// ---- y = x @ W ----
__global__ __launch_bounds__(128) void k_y(const float* __restrict__ x,
                                           const float* __restrict__ W,
                                           float* __restrict__ y) {
    int row = blockIdx.x, t = threadIdx.x;
    __shared__ float xs[FF];
    xs[t] = x[row * FF + t];
    __syncthreads();
    float acc = 0.f;
#pragma unroll 8
    for (int k = 0; k < FF; ++k) acc += xs[k] * W[k * FF + t];
    y[row * FF + t] = acc;
}

// ---- out block ----
__global__ __launch_bounds__(128) void k_out(const float* __restrict__ agg,
                                             const float* __restrict__ Wf,
                                             const float* __restrict__ bf,
                                             const float* __restrict__ Wd,
                                             const float* __restrict__ bd,
                                             float* __restrict__ x,
                                             float* __restrict__ out,
                                             int write_out) {
    int row = blockIdx.x, t = threadIdx.x;
    __shared__ float as_[FF];
    __shared__ float ts[FF];
    as_[t] = agg[row * FF + t];
    __syncthreads();
    float acc = bf[t];
#pragma unroll 8
    for (int k = 0; k < FF; ++k) acc += as_[k] * Wf[k * FF + t];
    ts[t] = ssp_f(acc);
    __syncthreads();
    float acc2 = bd[t];
#pragma unroll 8
    for (int k = 0; k < FF; ++k) acc2 += ts[k] * Wd[k * FF + t];
    float xn = x[row * FF + t] + acc2;
    x[row * FF + t] = xn;
    if (write_out) out[row * FF + t] = xn;
}

// LDS layout (dynamic, 76768 B):
//  [0,32768)      h bf16 [128n][128f], XOR-swizzled: byte = n*256 + ((f*2) ^ ((n&7)<<4))
//  [32768,65536)  W2T bf16 (linear copy of pre-swizzled global image)
//  [0,67040)      (epilogue alias) y fp32 [127][132]
//  [0,8192)       (final alias) reduction scratch 2048 f32
//  [67040,75232)  fij bf16 [128n][32g]
//  [75232,75744)  cm f32[128]; [75744,76256) nbr i32[128]; [76256,76768) r f32[128]
#define SMEM_BYTES 76768

__global__ __launch_bounds__(256, 2) void k_cfconv(
    const float* __restrict__ positions, const float* __restrict__ cell,
    const float* __restrict__ cell_offset, const float* __restrict__ nmask,
    const int* __restrict__ neighbors,
    const ushort_t* __restrict__ w1t, const float* __restrict__ b1,
    const ushort_t* __restrict__ w2s, const float* __restrict__ b2,
    const float* __restrict__ y, float* __restrict__ agg) {
    extern __shared__ char smem[];
    ushort_t* fij_s = (ushort_t*)(smem + 67040);
    float* cm_s = (float*)(smem + 75232);
    int* nbr_s = (int*)(smem + 75744);
    float* r_s = (float*)(smem + 76256);
    float* y_s = (float*)smem;
    float* red_s = (float*)smem;

    const int row = blockIdx.x;
    const int b = row >> 7;
    const int t = threadIdx.x;
    const int lane = t & 63, w = t >> 6;
    const int l15 = lane & 15, l4 = lane >> 4;

    // -- issue W2T global loads early (held in regs until LDS write) --
    uint4 wreg[8];
    {
        const uint4* wsrc = (const uint4*)w2s;
#pragma unroll
        for (int i = 0; i < 8; ++i) wreg[i] = wsrc[t + (i << 8)];
    }

    // -- phase 0a: distances + cutoff --
    if (t < NNB) {
        int nb = neighbors[row * NNB + t];
        nbr_s[t] = nb;
        float px = positions[row * 3 + 0], py = positions[row * 3 + 1], pz = positions[row * 3 + 2];
        int nrow = b * AA + nb;
        float qx = positions[nrow * 3 + 0], qy = positions[nrow * 3 + 1], qz = positions[nrow * 3 + 2];
        const float* co = cell_offset + (size_t)row * NNB * 3 + (size_t)t * 3;
        const float* cl = cell + b * 9;
        float c0 = co[0], c1 = co[1], c2 = co[2];
        float ox = c0 * cl[0] + c1 * cl[3] + c2 * cl[6];
        float oy = c0 * cl[1] + c1 * cl[4] + c2 * cl[7];
        float oz = c0 * cl[2] + c1 * cl[5] + c2 * cl[8];
        float dx = qx - px + ox, dy = qy - py + oy, dz = qz - pz + oz;
        float d2 = dx * dx + dy * dy + dz * dz;
        float mk = nmask[row * NNB + t];
        float r = (mk > 0.f) ? sqrtf(d2) : 0.f;
        r_s[t] = r;
        float Cc = 0.5f * (__cosf(r * (3.14159265358979323846f / 5.0f)) + 1.f);
        Cc = (r < 5.0f) ? Cc : 0.f;
        cm_s[t] = Cc * mk;
    } else if (t == NNB) {
        cm_s[NNB] = 0.f; nbr_s[NNB] = 0; r_s[NNB] = 1e9f;
    }
    __syncthreads();   // r_s ready

    // -- phase 0b: fij bf16 [128][32], packed u32 writes (2 gaussians each) --
    {
        const float width = 5.0f / (GG - 1);
        const float coeff = -0.5f / (width * width);
#pragma unroll
        for (int ii = 0; ii < 8; ++ii) {
            int idx = t + ii * 256;          // 0..2047
            int n = idx >> 4, gp = idx & 15; // g = 2*gp, 2*gp+1
            float rv = r_s[n];
            int g0 = gp << 1;
            float v0 = 0.f, v1 = 0.f;
            if (n < NNB) {
                float d0 = rv - g0 * width;
                float d1 = rv - (g0 + 1) * width;
                v0 = (g0 < GG) ? __expf(coeff * d0 * d0) : 0.f;
                v1 = (g0 + 1 < GG) ? __expf(coeff * d1 * d1) : 0.f;
            }
            *(unsigned int*)(fij_s + n * 32 + g0) = pack2bf(v0, v1);
        }
    }
    // -- write W2T tile to LDS --
    {
        uint4* wdst = (uint4*)(smem + 32768);
#pragma unroll
        for (int i = 0; i < 8; ++i) wdst[t + (i << 8)] = wreg[i];
    }
    __syncthreads();   // fij + W2T ready

    // -- phase 1 (SWAPPED): h^T blocks: D[f][n] = W1T(A) * fijT(B); rows=f => packable --
    {
        bf16x8 fb[2];
#pragma unroll
        for (int mi = 0; mi < 2; ++mi) {
            int n = (w << 5) + (mi << 4) + l15;
            fb[mi] = *(const bf16x8*)((const char*)fij_s + n * 64 + (l4 << 4));
        }
#pragma unroll
        for (int ft = 0; ft < 8; ++ft) {
            // A fragment: lane holds W1T[f = ft*16 + l15][g = l4*8 ..+8]
            bf16x8 aw = *(const bf16x8*)(w1t + ((ft << 4) + l15) * 32 + (l4 << 3));
            const int f0 = (ft << 4) + (l4 << 2);          // this lane's 4 output f rows
            f32x4 c0 = *(const f32x4*)(b1 + f0);           // per-reg b1
#pragma unroll
            for (int mi = 0; mi < 2; ++mi) {
                f32x4 d = __builtin_amdgcn_mfma_f32_16x16x32_bf16(aw, fb[mi], c0, 0, 0, 0);
                int n = (w << 5) + (mi << 4) + l15;
                int base = n * 256;
                int sw = (n & 7) << 4;
                float h0 = ssp_fast(d[0]), h1 = ssp_fast(d[1]);
                float h2 = ssp_fast(d[2]), h3 = ssp_fast(d[3]);
                *(unsigned int*)(smem + base + (((f0) << 1) ^ sw)) = pack2bf(h0, h1);
                *(unsigned int*)(smem + base + (((f0 + 2) << 1) ^ sw)) = pack2bf(h2, h3);
            }
        }
    }
    __syncthreads();   // h ready

    // -- phase 2: Wfilt = h @ W2 + b2 via MFMA (acc init = b2) --
    f32x4 acc[2][8];
#pragma unroll
    for (int ft = 0; ft < 8; ++ft) {
        float b2v = b2[(ft << 4) + l15];
        f32x4 c0 = {b2v, b2v, b2v, b2v};
        acc[0][ft] = c0;
        acc[1][ft] = c0;
    }
#pragma unroll
    for (int ks = 0; ks < 4; ++ks) {
        bf16x8 ha[2];
#pragma unroll
        for (int mi = 0; mi < 2; ++mi) {
            int n = (w << 5) + (mi << 4) + l15;
            int byte = n * 256 + ((((ks << 2) + l4) << 4) ^ ((n & 7) << 4));
            ha[mi] = *(const bf16x8*)(smem + byte);
        }
#pragma unroll
        for (int ft = 0; ft < 8; ++ft) {
            int f = (ft << 4) + l15;
            int byte = 32768 + f * 256 + ((((ks << 2) + l4) << 4) ^ ((f & 7) << 4));
            bf16x8 wb = *(const bf16x8*)(smem + byte);
            acc[0][ft] = __builtin_amdgcn_mfma_f32_16x16x32_bf16(ha[0], wb, acc[0][ft], 0, 0, 0);
            acc[1][ft] = __builtin_amdgcn_mfma_f32_16x16x32_bf16(ha[1], wb, acc[1][ft], 0, 0, 0);
        }
    }
    __syncthreads();   // all GEMM LDS reads done

    // -- stage y_nbh rows into LDS (fp32, stride 132) --
    {
        const int bA = b * AA;
        float4* yd4 = (float4*)smem;
        const float4* ysrc = (const float4*)y;
        for (int idx = t; idx < NNB * 32; idx += 256) {
            int n = idx >> 5, c = idx & 31;
            yd4[n * 33 + c] = ysrc[((size_t)(bA + nbr_s[n]) << 5) + c];
        }
    }
    __syncthreads();   // y_s ready

    // -- epilogue: part[f] += y * (acc * cm) --
    float part[8];
#pragma unroll
    for (int ft = 0; ft < 8; ++ft) part[ft] = 0.f;
#pragma unroll
    for (int mi = 0; mi < 2; ++mi) {
#pragma unroll
        for (int r = 0; r < 4; ++r) {
            int n = (w << 5) + (mi << 4) + (l4 << 2) + r;
            if (n < NNB) {
                float cmv = cm_s[n];
                const float* yrow = y_s + n * 132;
#pragma unroll
                for (int ft = 0; ft < 8; ++ft)
                    part[ft] = fmaf(yrow[(ft << 4) + l15], acc[mi][ft][r] * cmv, part[ft]);
            }
        }
    }
    __syncthreads();   // y reads done; safe to overwrite with red
#pragma unroll
    for (int ft = 0; ft < 8; ++ft)
        red_s[((w << 2) + l4) * 128 + (ft << 4) + l15] = part[ft];
    __syncthreads();
    if (t < FF) {
        float s = 0.f;
#pragma unroll
        for (int g = 0; g < 16; ++g) s += red_s[g * 128 + t];
        agg[(size_t)row * FF + t] = s;
    }
}

extern "C" void kernel_launch(void* const* d_in, const int* in_sizes, int n_in,
                              void* d_out, int out_size, void* d_ws, size_t ws_size,
                              hipStream_t stream) {
    const float* positions   = (const float*)d_in[0];
    const float* cell        = (const float*)d_in[1];
    const float* cell_offset = (const float*)d_in[2];
    const float* nmask       = (const float*)d_in[3];
    const float* emb         = (const float*)d_in[4];
    const float* filt_W1     = (const float*)d_in[5];
    const float* filt_b1     = (const float*)d_in[6];
    const float* filt_W2     = (const float*)d_in[7];
    const float* filt_b2     = (const float*)d_in[8];
    const float* in2f_W      = (const float*)d_in[9];
    const float* f2out_W     = (const float*)d_in[10];
    const float* f2out_b     = (const float*)d_in[11];
    const float* dense_W     = (const float*)d_in[12];
    const float* dense_b     = (const float*)d_in[13];
    const int* atomic_numbers = (const int*)d_in[14];
    const int* neighbors      = (const int*)d_in[15];
    float* out = (float*)d_out;

    float* x   = (float*)d_ws;
    float* yb  = x + BB * AA * FF;
    float* agg = yb + BB * AA * FF;
    ushort_t* w1t = (ushort_t*)(agg + BB * AA * FF);   // 3*128*32
    ushort_t* w2s = w1t + 3 * 128 * 32;                // 3*128*128

    k_prep<<<192, 256, 0, stream>>>(filt_W1, filt_W2, w1t, w2s);
    k_init_x<<<(BB * AA * FF + 255) / 256, 256, 0, stream>>>(emb, atomic_numbers, x);
    for (int l = 0; l < 3; ++l) {
        k_y<<<BB * AA, FF, 0, stream>>>(x, in2f_W + (size_t)l * FF * FF, yb);
        k_cfconv<<<BB * AA, 256, SMEM_BYTES, stream>>>(
            positions, cell, cell_offset, nmask, neighbors,
            w1t + (size_t)l * 128 * 32, filt_b1 + (size_t)l * FF,
            w2s + (size_t)l * 128 * 128, filt_b2 + (size_t)l * FF,
            yb, agg);
        k_out<<<BB * AA, FF, 0, stream>>>(agg, f2out_W + (size_t)l * FF * FF, f2out_b + (size_t)l * FF,
                                          dense_W + (size_t)l * FF * FF, dense_b + (size_t)l * FF,
                                          x, out, (l == 2) ? 1 : 0);
    }
}

// Round 6
// 198.014 us; speedup vs baseline: 4.3514x; 1.2971x over previous
//
#include <hip/hip_runtime.h>
#include <math.h>

#define BB 16
#define AA 128
#define NNB 127
#define FF 128
#define GG 25

typedef __attribute__((ext_vector_type(8))) short bf16x8;
typedef __attribute__((ext_vector_type(4))) float f32x4;
typedef unsigned short ushort_t;

#define GLOBAL_LOAD_LDS16(gp, lp)                                                        \
    __builtin_amdgcn_global_load_lds((const __attribute__((address_space(1))) unsigned int*)(gp), \
                                     (__attribute__((address_space(3))) unsigned int*)(lp), 16, 0, 0)

__device__ __forceinline__ float ssp_f(float x) {
    return fmaxf(x, 0.f) + log1pf(__expf(-fabsf(x))) - 0.6931471805599453f;
}

__device__ __forceinline__ float ssp_fast(float x) {
    float e = __expf(-fabsf(x));
    return fmaxf(x, 0.f) + __logf(1.f + e) - 0.6931471805599453f;
}

__device__ __forceinline__ ushort_t f2bf(float f) {
    unsigned int u = __float_as_uint(f);
    unsigned int r = (u + 0x7fffu + ((u >> 16) & 1u)) >> 16;
    return (ushort_t)r;
}

__device__ __forceinline__ unsigned int pack2bf(float lo, float hi) {
    return (unsigned int)f2bf(lo) | ((unsigned int)f2bf(hi) << 16);
}

// ---- prep: W1 -> W1T bf16 [3][128f][32g(pad0)]; W2 -> pre-swizzled W2T bf16 LDS image ----
__global__ __launch_bounds__(256) void k_prep(const float* __restrict__ W1,
                                              const float* __restrict__ W2,
                                              ushort_t* __restrict__ w1t,
                                              ushort_t* __restrict__ w2s) {
    int i = blockIdx.x * 256 + threadIdx.x;
    if (i < 3 * 128 * 32) {
        int l = i >> 12, rem = i & 4095, f = rem >> 5, g = rem & 31;
        float v = (g < GG) ? W1[l * GG * FF + g * FF + f] : 0.f;
        w1t[i] = f2bf(v);
    }
    if (i < 3 * 16384) {
        int l = i >> 14, rem = i & 16383, f = rem >> 7, k = rem & 127;
        // store so a LINEAR LDS copy yields the XOR-swizzled layout (read applies same XOR)
        w2s[l * 16384 + f * 128 + (k ^ ((f & 7) << 3))] = f2bf(W2[l * 16384 + k * FF + f]);
    }
}

// ---- x init ----
__global__ __launch_bounds__(256) void k_init_x(const float* __restrict__ emb,
                                                const int* __restrict__ z,
                                                float* __restrict__ x) {
    int i = blockIdx.x * 256 + threadIdx.x;
    if (i < BB * AA * FF) {
        int row = i >> 7, f = i & 127;
        x[i] = emb[z[row] * FF + f];
    }
}

// ---- y = x @ W, 4 rows per block (amortize W reads) ----
__global__ __launch_bounds__(128) void k_y(const float* __restrict__ x,
                                           const float* __restrict__ W,
                                           float* __restrict__ y) {
    int row0 = blockIdx.x << 2, t = threadIdx.x;
    __shared__ float xs[4][FF];
#pragma unroll
    for (int r = 0; r < 4; ++r) xs[r][t] = x[(row0 + r) * FF + t];
    __syncthreads();
    float acc[4] = {0.f, 0.f, 0.f, 0.f};
#pragma unroll 4
    for (int k = 0; k < FF; ++k) {
        float wv = W[k * FF + t];
        acc[0] = fmaf(xs[0][k], wv, acc[0]);
        acc[1] = fmaf(xs[1][k], wv, acc[1]);
        acc[2] = fmaf(xs[2][k], wv, acc[2]);
        acc[3] = fmaf(xs[3][k], wv, acc[3]);
    }
#pragma unroll
    for (int r = 0; r < 4; ++r) y[(row0 + r) * FF + t] = acc[r];
}

// ---- out block, 4 rows per block ----
__global__ __launch_bounds__(128) void k_out(const float* __restrict__ agg,
                                             const float* __restrict__ Wf,
                                             const float* __restrict__ bf,
                                             const float* __restrict__ Wd,
                                             const float* __restrict__ bd,
                                             float* __restrict__ x,
                                             float* __restrict__ out,
                                             int write_out) {
    int row0 = blockIdx.x << 2, t = threadIdx.x;
    __shared__ float as_[4][FF];
    __shared__ float ts[4][FF];
#pragma unroll
    for (int r = 0; r < 4; ++r) as_[r][t] = agg[(row0 + r) * FF + t];
    __syncthreads();
    {
        float a0 = bf[t], a1 = a0, a2 = a0, a3 = a0;
#pragma unroll 4
        for (int k = 0; k < FF; ++k) {
            float wv = Wf[k * FF + t];
            a0 = fmaf(as_[0][k], wv, a0);
            a1 = fmaf(as_[1][k], wv, a1);
            a2 = fmaf(as_[2][k], wv, a2);
            a3 = fmaf(as_[3][k], wv, a3);
        }
        ts[0][t] = ssp_f(a0); ts[1][t] = ssp_f(a1);
        ts[2][t] = ssp_f(a2); ts[3][t] = ssp_f(a3);
    }
    __syncthreads();
    {
        float a0 = bd[t], a1 = a0, a2 = a0, a3 = a0;
#pragma unroll 4
        for (int k = 0; k < FF; ++k) {
            float wv = Wd[k * FF + t];
            a0 = fmaf(ts[0][k], wv, a0);
            a1 = fmaf(ts[1][k], wv, a1);
            a2 = fmaf(ts[2][k], wv, a2);
            a3 = fmaf(ts[3][k], wv, a3);
        }
        float xn0 = x[(row0 + 0) * FF + t] + a0;
        float xn1 = x[(row0 + 1) * FF + t] + a1;
        float xn2 = x[(row0 + 2) * FF + t] + a2;
        float xn3 = x[(row0 + 3) * FF + t] + a3;
        x[(row0 + 0) * FF + t] = xn0; x[(row0 + 1) * FF + t] = xn1;
        x[(row0 + 2) * FF + t] = xn2; x[(row0 + 3) * FF + t] = xn3;
        if (write_out) {
            out[(row0 + 0) * FF + t] = xn0; out[(row0 + 1) * FF + t] = xn1;
            out[(row0 + 2) * FF + t] = xn2; out[(row0 + 3) * FF + t] = xn3;
        }
    }
}

// LDS layout (dynamic, 75264 B):
//  [0,32768)      h bf16 [128n][128f], XOR-swizzled: byte = n*256 + ((f*2) ^ ((n&7)<<4))
//  [32768,65536)  W2T bf16 (linear global_load_lds copy of pre-swizzled global image)
//  [0,65536)      (epilogue alias) y fp32 [128 rows][128], elem ^= (n&7)<<2 swizzle
//  [0,8192)       (final alias) reduction scratch, dword = g*128 + ((f) ^ ((g&3)<<3))
//  [65536,73728)  fij bf16 [128n][32g]
//  [73728,74240)  cm f32[128]; [74240,74752) nbr i32[128]; [74752,75264) r f32[128]
#define SMEM_BYTES 75264

__global__ __launch_bounds__(256, 2) void k_cfconv(
    const float* __restrict__ positions, const float* __restrict__ cell,
    const float* __restrict__ cell_offset, const float* __restrict__ nmask,
    const int* __restrict__ neighbors,
    const ushort_t* __restrict__ w1t, const float* __restrict__ b1,
    const ushort_t* __restrict__ w2s, const float* __restrict__ b2,
    const float* __restrict__ y, float* __restrict__ agg) {
    extern __shared__ char smem[];
    ushort_t* fij_s = (ushort_t*)(smem + 65536);
    float* cm_s = (float*)(smem + 73728);
    int* nbr_s = (int*)(smem + 74240);
    float* r_s = (float*)(smem + 74752);
    float* y_s = (float*)smem;
    float* red_s = (float*)smem;

    const int row = blockIdx.x;
    const int b = row >> 7;
    const int t = threadIdx.x;
    const int lane = t & 63, w = t >> 6;
    const int l15 = lane & 15, l4 = lane >> 4;

    // -- issue async W2T global->LDS at entry (no VGPRs, lands before phase 2) --
    {
        const char* gsrc = (const char*)w2s;
#pragma unroll
        for (int i = 0; i < 8; ++i) {
            int blk = (w << 3) + i;                       // 0..31, 1 KiB each
            GLOBAL_LOAD_LDS16(gsrc + (blk << 10) + (lane << 4), smem + 32768 + (blk << 10));
        }
    }

    // -- phase 0a: distances + cutoff --
    if (t < NNB) {
        int nb = neighbors[row * NNB + t];
        nbr_s[t] = nb;
        float px = positions[row * 3 + 0], py = positions[row * 3 + 1], pz = positions[row * 3 + 2];
        int nrow = b * AA + nb;
        float qx = positions[nrow * 3 + 0], qy = positions[nrow * 3 + 1], qz = positions[nrow * 3 + 2];
        const float* co = cell_offset + (size_t)row * NNB * 3 + (size_t)t * 3;
        const float* cl = cell + b * 9;
        float c0 = co[0], c1 = co[1], c2 = co[2];
        float ox = c0 * cl[0] + c1 * cl[3] + c2 * cl[6];
        float oy = c0 * cl[1] + c1 * cl[4] + c2 * cl[7];
        float oz = c0 * cl[2] + c1 * cl[5] + c2 * cl[8];
        float dx = qx - px + ox, dy = qy - py + oy, dz = qz - pz + oz;
        float d2 = dx * dx + dy * dy + dz * dz;
        float mk = nmask[row * NNB + t];
        float r = (mk > 0.f) ? sqrtf(d2) : 0.f;
        r_s[t] = r;
        float Cc = 0.5f * (__cosf(r * (3.14159265358979323846f / 5.0f)) + 1.f);
        Cc = (r < 5.0f) ? Cc : 0.f;
        cm_s[t] = Cc * mk;
    } else if (t == NNB) {
        cm_s[NNB] = 0.f; nbr_s[NNB] = 0; r_s[NNB] = 1e9f;
    }
    __syncthreads();   // r_s, nbr_s ready

    // -- phase 0b: fij bf16 [128][32], packed u32 writes --
    {
        const float width = 5.0f / (GG - 1);
        const float coeff = -0.5f / (width * width);
#pragma unroll
        for (int ii = 0; ii < 8; ++ii) {
            int idx = t + ii * 256;          // 0..2047
            int n = idx >> 4, gp = idx & 15;
            float rv = r_s[n];
            int g0 = gp << 1;
            float v0 = 0.f, v1 = 0.f;
            if (n < NNB) {
                float d0 = rv - g0 * width;
                float d1 = rv - (g0 + 1) * width;
                v0 = (g0 < GG) ? __expf(coeff * d0 * d0) : 0.f;
                v1 = (g0 + 1 < GG) ? __expf(coeff * d1 * d1) : 0.f;
            }
            *(unsigned int*)(fij_s + n * 32 + g0) = pack2bf(v0, v1);
        }
    }
    __syncthreads();   // fij ready

    // -- phase 1 (swapped operands): D[f][n] = W1T * fijT ; ssp ; b64 swizzled h write --
    {
        bf16x8 fb[2];
#pragma unroll
        for (int mi = 0; mi < 2; ++mi) {
            int n = (w << 5) + (mi << 4) + l15;
            fb[mi] = *(const bf16x8*)((const char*)fij_s + n * 64 + (l4 << 4));
        }
#pragma unroll
        for (int ft = 0; ft < 8; ++ft) {
            bf16x8 aw = *(const bf16x8*)(w1t + ((ft << 4) + l15) * 32 + (l4 << 3));
            const int f0 = (ft << 4) + (l4 << 2);
            f32x4 c0 = *(const f32x4*)(b1 + f0);
#pragma unroll
            for (int mi = 0; mi < 2; ++mi) {
                f32x4 d = __builtin_amdgcn_mfma_f32_16x16x32_bf16(aw, fb[mi], c0, 0, 0, 0);
                int n = (w << 5) + (mi << 4) + l15;
                int base = n * 256;
                int sw = (n & 7) << 4;
                unsigned long long pk =
                    (unsigned long long)pack2bf(ssp_fast(d[0]), ssp_fast(d[1])) |
                    ((unsigned long long)pack2bf(ssp_fast(d[2]), ssp_fast(d[3])) << 32);
                *(unsigned long long*)(smem + base + ((f0 << 1) ^ sw)) = pk;
            }
        }
    }
    __syncthreads();   // h ready; vmcnt drained => W2T in LDS

    // -- phase 2: Wfilt = h @ W2 + b2 via MFMA --
    f32x4 acc[2][8];
#pragma unroll
    for (int ft = 0; ft < 8; ++ft) {
        float b2v = b2[(ft << 4) + l15];
        f32x4 c0 = {b2v, b2v, b2v, b2v};
        acc[0][ft] = c0;
        acc[1][ft] = c0;
    }
#pragma unroll
    for (int ks = 0; ks < 4; ++ks) {
        bf16x8 ha[2];
#pragma unroll
        for (int mi = 0; mi < 2; ++mi) {
            int n = (w << 5) + (mi << 4) + l15;
            int byte = n * 256 + ((((ks << 2) + l4) << 4) ^ ((n & 7) << 4));
            ha[mi] = *(const bf16x8*)(smem + byte);
        }
#pragma unroll
        for (int ft = 0; ft < 8; ++ft) {
            int f = (ft << 4) + l15;
            int byte = 32768 + f * 256 + ((((ks << 2) + l4) << 4) ^ ((f & 7) << 4));
            bf16x8 wb = *(const bf16x8*)(smem + byte);
            acc[0][ft] = __builtin_amdgcn_mfma_f32_16x16x32_bf16(ha[0], wb, acc[0][ft], 0, 0, 0);
            acc[1][ft] = __builtin_amdgcn_mfma_f32_16x16x32_bf16(ha[1], wb, acc[1][ft], 0, 0, 0);
        }
    }
    __syncthreads();   // all GEMM LDS reads done; safe to overwrite h/W2 with y

    // -- stage y_nbh via global_load_lds: dest rows linear, source pre-swizzled per lane --
    {
        const int bA = b * AA;
#pragma unroll
        for (int ii = 0; ii < 16; ++ii) {
            int i = (w << 4) + ii;               // pair 0..63
            int n = (i << 1) + (lane >> 5);      // dest row 0..127
            int nb = nbr_s[n];
            int e0 = ((lane & 31) << 2) ^ ((n & 7) << 2);
            const float* gp = y + (((size_t)(bA + nb)) << 7) + e0;
            GLOBAL_LOAD_LDS16(gp, smem + (i << 10));
        }
    }
    __syncthreads();   // vmcnt drained => y_s ready

    // -- epilogue: part[f] += y * (acc * cm), swizzled y reads --
    float part[8];
#pragma unroll
    for (int ft = 0; ft < 8; ++ft) part[ft] = 0.f;
#pragma unroll
    for (int mi = 0; mi < 2; ++mi) {
#pragma unroll
        for (int r = 0; r < 4; ++r) {
            int n = (w << 5) + (mi << 4) + (l4 << 2) + r;
            if (n < NNB) {
                float cmv = cm_s[n];
                const float* yrow = y_s + (n << 7);
                int sx = (n & 7) << 2;
#pragma unroll
                for (int ft = 0; ft < 8; ++ft)
                    part[ft] = fmaf(yrow[((ft << 4) + l15) ^ sx], acc[mi][ft][r] * cmv, part[ft]);
            }
        }
    }
    __syncthreads();   // y reads done; safe to overwrite rows 0..15 with red
    {
        int g = (w << 2) + l4;
        int xg = (g & 3) << 3;
#pragma unroll
        for (int ft = 0; ft < 8; ++ft)
            red_s[(g << 7) + ((((ft << 4) + l15)) ^ xg)] = part[ft];
    }
    __syncthreads();
    if (t < FF) {
        float s = 0.f;
#pragma unroll
        for (int g = 0; g < 16; ++g) s += red_s[(g << 7) + (t ^ ((g & 3) << 3))];
        agg[(size_t)row * FF + t] = s;
    }
}

extern "C" void kernel_launch(void* const* d_in, const int* in_sizes, int n_in,
                              void* d_out, int out_size, void* d_ws, size_t ws_size,
                              hipStream_t stream) {
    const float* positions   = (const float*)d_in[0];
    const float* cell        = (const float*)d_in[1];
    const float* cell_offset = (const float*)d_in[2];
    const float* nmask       = (const float*)d_in[3];
    const float* emb         = (const float*)d_in[4];
    const float* filt_W1     = (const float*)d_in[5];
    const float* filt_b1     = (const float*)d_in[6];
    const float* filt_W2     = (const float*)d_in[7];
    const float* filt_b2     = (const float*)d_in[8];
    const float* in2f_W      = (const float*)d_in[9];
    const float* f2out_W     = (const float*)d_in[10];
    const float* f2out_b     = (const float*)d_in[11];
    const float* dense_W     = (const float*)d_in[12];
    const float* dense_b     = (const float*)d_in[13];
    const int* atomic_numbers = (const int*)d_in[14];
    const int* neighbors      = (const int*)d_in[15];
    float* out = (float*)d_out;

    float* x   = (float*)d_ws;
    float* yb  = x + BB * AA * FF;
    float* agg = yb + BB * AA * FF;
    ushort_t* w1t = (ushort_t*)(agg + BB * AA * FF);   // 3*128*32
    ushort_t* w2s = w1t + 3 * 128 * 32;                // 3*128*128

    k_prep<<<192, 256, 0, stream>>>(filt_W1, filt_W2, w1t, w2s);
    k_init_x<<<(BB * AA * FF + 255) / 256, 256, 0, stream>>>(emb, atomic_numbers, x);
    for (int l = 0; l < 3; ++l) {
        k_y<<<BB * AA / 4, FF, 0, stream>>>(x, in2f_W + (size_t)l * FF * FF, yb);
        k_cfconv<<<BB * AA, 256, SMEM_BYTES, stream>>>(
            positions, cell, cell_offset, nmask, neighbors,
            w1t + (size_t)l * 128 * 32, filt_b1 + (size_t)l * FF,
            w2s + (size_t)l * 128 * 128, filt_b2 + (size_t)l * FF,
            yb, agg);
        k_out<<<BB * AA / 4, FF, 0, stream>>>(agg, f2out_W + (size_t)l * FF * FF, f2out_b + (size_t)l * FF,
                                              dense_W + (size_t)l * FF * FF, dense_b + (size_t)l * FF,
                                              x, out, (l == 2) ? 1 : 0);
    }
}

// Round 8
// 195.253 us; speedup vs baseline: 4.4129x; 1.0141x over previous
//
#include <hip/hip_runtime.h>
#include <math.h>

#define BB 16
#define AA 128
#define NNB 127
#define FF 128
#define GG 25

typedef __attribute__((ext_vector_type(8))) short bf16x8;
typedef __attribute__((ext_vector_type(4))) float f32x4;
typedef unsigned short ushort_t;

#define GLOBAL_LOAD_LDS16(gp, lp)                                                        \
    __builtin_amdgcn_global_load_lds((const __attribute__((address_space(1))) unsigned int*)(gp), \
                                     (__attribute__((address_space(3))) unsigned int*)(lp), 16, 0, 0)

__device__ __forceinline__ float ssp_f(float x) {
    return fmaxf(x, 0.f) + log1pf(__expf(-fabsf(x))) - 0.6931471805599453f;
}

__device__ __forceinline__ float ssp_fast(float x) {
    float e = __expf(-fabsf(x));
    return fmaxf(x, 0.f) + __logf(1.f + e) - 0.6931471805599453f;
}

__device__ __forceinline__ ushort_t f2bf(float f) {
    unsigned int u = __float_as_uint(f);
    unsigned int r = (u + 0x7fffu + ((u >> 16) & 1u)) >> 16;
    return (ushort_t)r;
}

__device__ __forceinline__ unsigned int pack2bf(float lo, float hi) {
    return (unsigned int)f2bf(lo) | ((unsigned int)f2bf(hi) << 16);
}

// ---- prep: W1 -> W1T bf16 [3][128f][32g(pad0)]; W2 -> pre-swizzled W2T bf16 LDS image ----
__global__ __launch_bounds__(256) void k_prep(const float* __restrict__ W1,
                                              const float* __restrict__ W2,
                                              ushort_t* __restrict__ w1t,
                                              ushort_t* __restrict__ w2s) {
    int i = blockIdx.x * 256 + threadIdx.x;
    if (i < 3 * 128 * 32) {
        int l = i >> 12, rem = i & 4095, f = rem >> 5, g = rem & 31;
        float v = (g < GG) ? W1[l * GG * FF + g * FF + f] : 0.f;
        w1t[i] = f2bf(v);
    }
    if (i < 3 * 16384) {
        int l = i >> 14, rem = i & 16383, f = rem >> 7, k = rem & 127;
        w2s[l * 16384 + f * 128 + (k ^ ((f & 7) << 3))] = f2bf(W2[l * 16384 + k * FF + f]);
    }
}

// ---- x init ----
__global__ __launch_bounds__(256) void k_init_x(const float* __restrict__ emb,
                                                const int* __restrict__ z,
                                                float* __restrict__ x) {
    int i = blockIdx.x * 256 + threadIdx.x;
    if (i < BB * AA * FF) {
        int row = i >> 7, f = i & 127;
        x[i] = emb[z[row] * FF + f];
    }
}

// ---- y = x @ W, 4 rows per block ----
__global__ __launch_bounds__(128) void k_y(const float* __restrict__ x,
                                           const float* __restrict__ W,
                                           float* __restrict__ y) {
    int row0 = blockIdx.x << 2, t = threadIdx.x;
    __shared__ float xs[4][FF];
#pragma unroll
    for (int r = 0; r < 4; ++r) xs[r][t] = x[(row0 + r) * FF + t];
    __syncthreads();
    float acc[4] = {0.f, 0.f, 0.f, 0.f};
#pragma unroll 4
    for (int k = 0; k < FF; ++k) {
        float wv = W[k * FF + t];
        acc[0] = fmaf(xs[0][k], wv, acc[0]);
        acc[1] = fmaf(xs[1][k], wv, acc[1]);
        acc[2] = fmaf(xs[2][k], wv, acc[2]);
        acc[3] = fmaf(xs[3][k], wv, acc[3]);
    }
#pragma unroll
    for (int r = 0; r < 4; ++r) y[(row0 + r) * FF + t] = acc[r];
}

// ---- out block, 4 rows per block ----
__global__ __launch_bounds__(128) void k_out(const float* __restrict__ agg,
                                             const float* __restrict__ Wf,
                                             const float* __restrict__ bf,
                                             const float* __restrict__ Wd,
                                             const float* __restrict__ bd,
                                             float* __restrict__ x,
                                             float* __restrict__ out,
                                             int write_out) {
    int row0 = blockIdx.x << 2, t = threadIdx.x;
    __shared__ float as_[4][FF];
    __shared__ float ts[4][FF];
#pragma unroll
    for (int r = 0; r < 4; ++r) as_[r][t] = agg[(row0 + r) * FF + t];
    __syncthreads();
    {
        float a0 = bf[t], a1 = a0, a2 = a0, a3 = a0;
#pragma unroll 4
        for (int k = 0; k < FF; ++k) {
            float wv = Wf[k * FF + t];
            a0 = fmaf(as_[0][k], wv, a0);
            a1 = fmaf(as_[1][k], wv, a1);
            a2 = fmaf(as_[2][k], wv, a2);
            a3 = fmaf(as_[3][k], wv, a3);
        }
        ts[0][t] = ssp_f(a0); ts[1][t] = ssp_f(a1);
        ts[2][t] = ssp_f(a2); ts[3][t] = ssp_f(a3);
    }
    __syncthreads();
    {
        float a0 = bd[t], a1 = a0, a2 = a0, a3 = a0;
#pragma unroll 4
        for (int k = 0; k < FF; ++k) {
            float wv = Wd[k * FF + t];
            a0 = fmaf(ts[0][k], wv, a0);
            a1 = fmaf(ts[1][k], wv, a1);
            a2 = fmaf(ts[2][k], wv, a2);
            a3 = fmaf(ts[3][k], wv, a3);
        }
        float xn0 = x[(row0 + 0) * FF + t] + a0;
        float xn1 = x[(row0 + 1) * FF + t] + a1;
        float xn2 = x[(row0 + 2) * FF + t] + a2;
        float xn3 = x[(row0 + 3) * FF + t] + a3;
        x[(row0 + 0) * FF + t] = xn0; x[(row0 + 1) * FF + t] = xn1;
        x[(row0 + 2) * FF + t] = xn2; x[(row0 + 3) * FF + t] = xn3;
        if (write_out) {
            out[(row0 + 0) * FF + t] = xn0; out[(row0 + 1) * FF + t] = xn1;
            out[(row0 + 2) * FF + t] = xn2; out[(row0 + 3) * FF + t] = xn3;
        }
    }
}

// LDS layout (dynamic, 75264 B), 512-thread version:
//  [0,32768)      h bf16 [128n][128f], swizzled: byte = n*256 + ((f*2) ^ ((n&7)<<4))
//  [32768,65536)  W2T bf16 (linear global_load_lds copy of pre-swizzled global image)
//  [0,65536)      (epilogue alias) y fp32 [128 rows][128], elem ^= (n&7)<<2 swizzle
//  [0,16384)      (final alias) red: 32 groups x 128f, dword = g*128 + (f ^ ((g&3)<<3))
//  [16384,18432)  red2: 4 x 128 f32
//  [65536,73728)  fij bf16 [128n][32g]
//  [73728,74240)  cm f32[128]; [74240,74752) nbr i32[128]; [74752,75264) r f32[128]
#define SMEM_BYTES 75264

__global__ __launch_bounds__(512, 4) void k_cfconv(
    const float* __restrict__ positions, const float* __restrict__ cell,
    const float* __restrict__ cell_offset, const float* __restrict__ nmask,
    const int* __restrict__ neighbors,
    const ushort_t* __restrict__ w1t, const float* __restrict__ b1,
    const ushort_t* __restrict__ w2s, const float* __restrict__ b2,
    const float* __restrict__ y, float* __restrict__ agg) {
    extern __shared__ char smem[];
    ushort_t* fij_s = (ushort_t*)(smem + 65536);
    float* cm_s = (float*)(smem + 73728);
    int* nbr_s = (int*)(smem + 74240);
    float* r_s = (float*)(smem + 74752);
    float* y_s = (float*)smem;
    float* red_s = (float*)smem;
    float* red2_s = (float*)(smem + 16384);

    const int row = blockIdx.x;
    const int b = row >> 7;
    const int t = threadIdx.x;
    const int lane = t & 63, w = t >> 6;       // 8 waves
    const int l15 = lane & 15, l4 = lane >> 4;

    // -- async W2T global->LDS at entry: 32 x 1KiB blocks, 4 per wave --
    {
        const char* gsrc = (const char*)w2s;
#pragma unroll
        for (int i = 0; i < 4; ++i) {
            int blk = (w << 2) + i;
            GLOBAL_LOAD_LDS16(gsrc + (blk << 10) + (lane << 4), smem + 32768 + (blk << 10));
        }
    }

    // -- phase 0a: distances + cutoff --
    if (t < NNB) {
        int nb = neighbors[row * NNB + t];
        nbr_s[t] = nb;
        float px = positions[row * 3 + 0], py = positions[row * 3 + 1], pz = positions[row * 3 + 2];
        int nrow = b * AA + nb;
        float qx = positions[nrow * 3 + 0], qy = positions[nrow * 3 + 1], qz = positions[nrow * 3 + 2];
        const float* co = cell_offset + (size_t)row * NNB * 3 + (size_t)t * 3;
        const float* cl = cell + b * 9;
        float c0 = co[0], c1 = co[1], c2 = co[2];
        float ox = c0 * cl[0] + c1 * cl[3] + c2 * cl[6];
        float oy = c0 * cl[1] + c1 * cl[4] + c2 * cl[7];
        float oz = c0 * cl[2] + c1 * cl[5] + c2 * cl[8];
        float dx = qx - px + ox, dy = qy - py + oy, dz = qz - pz + oz;
        float d2 = dx * dx + dy * dy + dz * dz;
        float mk = nmask[row * NNB + t];
        float r = (mk > 0.f) ? sqrtf(d2) : 0.f;
        r_s[t] = r;
        float Cc = 0.5f * (__cosf(r * (3.14159265358979323846f / 5.0f)) + 1.f);
        Cc = (r < 5.0f) ? Cc : 0.f;
        cm_s[t] = Cc * mk;
    } else if (t == NNB) {
        cm_s[NNB] = 0.f; nbr_s[NNB] = 0; r_s[NNB] = 1e9f;
    }
    __syncthreads();   // r_s, nbr_s ready

    // -- phase 0b: fij bf16 [128][32], packed u32 writes --
    {
        const float width = 5.0f / (GG - 1);
        const float coeff = -0.5f / (width * width);
#pragma unroll
        for (int ii = 0; ii < 4; ++ii) {
            int idx = t + ii * 512;          // 0..2047
            int n = idx >> 4, gp = idx & 15;
            float rv = r_s[n];
            int g0 = gp << 1;
            float v0 = 0.f, v1 = 0.f;
            if (n < NNB) {
                float d0 = rv - g0 * width;
                float d1 = rv - (g0 + 1) * width;
                v0 = (g0 < GG) ? __expf(coeff * d0 * d0) : 0.f;
                v1 = (g0 + 1 < GG) ? __expf(coeff * d1 * d1) : 0.f;
            }
            *(unsigned int*)(fij_s + n * 32 + g0) = pack2bf(v0, v1);
        }
    }
    __syncthreads();   // fij ready

    // -- phase 1 (swapped operands): D[f][n] = W1T * fijT ; ssp ; b64 swizzled h write --
    {
        const int nrow = (w << 4) + l15;
        bf16x8 fb = *(const bf16x8*)((const char*)fij_s + nrow * 64 + (l4 << 4));
        const int base = nrow * 256;
        const int sw = (nrow & 7) << 4;
#pragma unroll
        for (int ft = 0; ft < 8; ++ft) {
            bf16x8 aw = *(const bf16x8*)(w1t + ((ft << 4) + l15) * 32 + (l4 << 3));
            const int f0 = (ft << 4) + (l4 << 2);
            f32x4 c0 = *(const f32x4*)(b1 + f0);
            f32x4 d = __builtin_amdgcn_mfma_f32_16x16x32_bf16(aw, fb, c0, 0, 0, 0);
            unsigned long long pk =
                (unsigned long long)pack2bf(ssp_fast(d[0]), ssp_fast(d[1])) |
                ((unsigned long long)pack2bf(ssp_fast(d[2]), ssp_fast(d[3])) << 32);
            *(unsigned long long*)(smem + base + ((f0 << 1) ^ sw)) = pk;
        }
    }
    __syncthreads();   // h ready; vmcnt drained => W2T in LDS

    // -- phase 2: Wfilt = h @ W2 + b2 via MFMA (each wave: 16 rows, 32 MFMA) --
    f32x4 acc[8];
#pragma unroll
    for (int ft = 0; ft < 8; ++ft) {
        float b2v = b2[(ft << 4) + l15];
        f32x4 c0 = {b2v, b2v, b2v, b2v};
        acc[ft] = c0;
    }
    {
        const int nrow = (w << 4) + l15;
        const int hbase = nrow * 256;
        const int hsw = (nrow & 7) << 4;
#pragma unroll
        for (int ks = 0; ks < 4; ++ks) {
            bf16x8 ha = *(const bf16x8*)(smem + hbase + ((((ks << 2) + l4) << 4) ^ hsw));
#pragma unroll
            for (int ft = 0; ft < 8; ++ft) {
                int f = (ft << 4) + l15;
                int byte = 32768 + f * 256 + ((((ks << 2) + l4) << 4) ^ ((f & 7) << 4));
                bf16x8 wb = *(const bf16x8*)(smem + byte);
                acc[ft] = __builtin_amdgcn_mfma_f32_16x16x32_bf16(ha, wb, acc[ft], 0, 0, 0);
            }
        }
    }
    __syncthreads();   // all GEMM LDS reads done; safe to overwrite h/W2 with y

    // -- stage y_nbh via global_load_lds: dest linear, source pre-swizzled per lane --
    {
        const int bA = b * AA;
#pragma unroll
        for (int ii = 0; ii < 8; ++ii) {
            int c = t + (ii << 9);               // chunk 0..4095 (16B each)
            int n = c >> 5, sub = c & 31;
            int nb = nbr_s[n];
            int e0 = (sub << 2) ^ ((n & 7) << 2);
            const float* gp = y + (((size_t)(bA + nb)) << 7) + e0;
            GLOBAL_LOAD_LDS16(gp, smem + ((size_t)c << 4));
        }
    }
    __syncthreads();   // vmcnt drained => y_s ready

    // -- epilogue: part[f] += y * (acc * cm), swizzled y reads --
    float part[8];
#pragma unroll
    for (int ft = 0; ft < 8; ++ft) part[ft] = 0.f;
#pragma unroll
    for (int r = 0; r < 4; ++r) {
        int n = (w << 4) + (l4 << 2) + r;
        if (n < NNB) {
            float cmv = cm_s[n];
            const float* yrow = y_s + (n << 7);
            int sx = (n & 7) << 2;
#pragma unroll
            for (int ft = 0; ft < 8; ++ft)
                part[ft] = fmaf(yrow[((ft << 4) + l15) ^ sx], acc[ft][r] * cmv, part[ft]);
        }
    }
    __syncthreads();   // y reads done; safe to overwrite with red
    {
        int g = (w << 2) + l4;                   // 0..31
        int xg = (g & 3) << 3;
#pragma unroll
        for (int ft = 0; ft < 8; ++ft)
            red_s[(g << 7) + ((((ft << 4) + l15)) ^ xg)] = part[ft];
    }
    __syncthreads();
    // stage 1: 4 groups of 8
    {
        int q = t >> 7, f = t & 127;
        float s = 0.f;
#pragma unroll
        for (int j = 0; j < 8; ++j) {
            int g = (q << 3) + j;
            s += red_s[(g << 7) + (f ^ ((g & 3) << 3))];
        }
        red2_s[(q << 7) + f] = s;
    }
    __syncthreads();
    if (t < FF)
        agg[(size_t)row * FF + t] = red2_s[t] + red2_s[128 + t] + red2_s[256 + t] + red2_s[384 + t];
}

extern "C" void kernel_launch(void* const* d_in, const int* in_sizes, int n_in,
                              void* d_out, int out_size, void* d_ws, size_t ws_size,
                              hipStream_t stream) {
    const float* positions   = (const float*)d_in[0];
    const float* cell        = (const float*)d_in[1];
    const float* cell_offset = (const float*)d_in[2];
    const float* nmask       = (const float*)d_in[3];
    const float* emb         = (const float*)d_in[4];
    const float* filt_W1     = (const float*)d_in[5];
    const float* filt_b1     = (const float*)d_in[6];
    const float* filt_W2     = (const float*)d_in[7];
    const float* filt_b2     = (const float*)d_in[8];
    const float* in2f_W      = (const float*)d_in[9];
    const float* f2out_W     = (const float*)d_in[10];
    const float* f2out_b     = (const float*)d_in[11];
    const float* dense_W     = (const float*)d_in[12];
    const float* dense_b     = (const float*)d_in[13];
    const int* atomic_numbers = (const int*)d_in[14];
    const int* neighbors      = (const int*)d_in[15];
    float* out = (float*)d_out;

    float* x   = (float*)d_ws;
    float* yb  = x + BB * AA * FF;
    float* agg = yb + BB * AA * FF;
    ushort_t* w1t = (ushort_t*)(agg + BB * AA * FF);   // 3*128*32
    ushort_t* w2s = w1t + 3 * 128 * 32;                // 3*128*128

    k_prep<<<192, 256, 0, stream>>>(filt_W1, filt_W2, w1t, w2s);
    k_init_x<<<(BB * AA * FF + 255) / 256, 256, 0, stream>>>(emb, atomic_numbers, x);
    for (int l = 0; l < 3; ++l) {
        k_y<<<BB * AA / 4, FF, 0, stream>>>(x, in2f_W + (size_t)l * FF * FF, yb);
        k_cfconv<<<BB * AA, 512, SMEM_BYTES, stream>>>(
            positions, cell, cell_offset, nmask, neighbors,
            w1t + (size_t)l * 128 * 32, filt_b1 + (size_t)l * FF,
            w2s + (size_t)l * 128 * 128, filt_b2 + (size_t)l * FF,
            yb, agg);
        k_out<<<BB * AA / 4, FF, 0, stream>>>(agg, f2out_W + (size_t)l * FF * FF, f2out_b + (size_t)l * FF,
                                              dense_W + (size_t)l * FF * FF, dense_b + (size_t)l * FF,
                                              x, out, (l == 2) ? 1 : 0);
    }
}

// Round 9
// 153.945 us; speedup vs baseline: 5.5970x; 1.2683x over previous
//
#include <hip/hip_runtime.h>
#include <math.h>

#define BB 16
#define AA 128
#define NNB 127
#define FF 128
#define GG 25

typedef __attribute__((ext_vector_type(8))) short bf16x8;
typedef __attribute__((ext_vector_type(4))) float f32x4;
typedef unsigned short ushort_t;

#define GLOBAL_LOAD_LDS16(gp, lp)                                                        \
    __builtin_amdgcn_global_load_lds((const __attribute__((address_space(1))) unsigned int*)(gp), \
                                     (__attribute__((address_space(3))) unsigned int*)(lp), 16, 0, 0)

__device__ __forceinline__ float ssp_f(float x) {
    return fmaxf(x, 0.f) + log1pf(__expf(-fabsf(x))) - 0.6931471805599453f;
}

// softplus(x)-ln2 with poly log1p: 1 trans op. |err| <= ~1e-5 (Hastings deg-5 on [0,1])
__device__ __forceinline__ float ssp_fast(float x) {
    float e = __expf(-fabsf(x));
    float p = fmaf(e, 0.03215845f, -0.13606275f);
    p = fmaf(e, p, 0.28947478f);
    p = fmaf(e, p, -0.49190896f);
    p = fmaf(e, p, 0.99949556f);
    return fmaxf(x, 0.f) + e * p - 0.6931471805599453f;
}

__device__ __forceinline__ ushort_t f2bf(float f) {
    unsigned int u = __float_as_uint(f);
    unsigned int r = (u + 0x7fffu + ((u >> 16) & 1u)) >> 16;
    return (ushort_t)r;
}

__device__ __forceinline__ float bf2f(ushort_t h) {
    return __uint_as_float(((unsigned int)h) << 16);
}

__device__ __forceinline__ unsigned int pack2bf(float lo, float hi) {
    return (unsigned int)f2bf(lo) | ((unsigned int)f2bf(hi) << 16);
}

// ---- prep: W1T bf16; W2 pre-swizzled; ffn weights hi/lo split bf16, transposed [f][k] ----
__global__ __launch_bounds__(256) void k_prep(const float* __restrict__ W1,
                                              const float* __restrict__ W2,
                                              const float* __restrict__ Win,
                                              const float* __restrict__ Wf,
                                              const float* __restrict__ Wd,
                                              ushort_t* __restrict__ w1t,
                                              ushort_t* __restrict__ w2s,
                                              ushort_t* __restrict__ whi,
                                              ushort_t* __restrict__ wlo) {
    int i = blockIdx.x * 256 + threadIdx.x;
    if (i < 3 * 128 * 32) {
        int l = i >> 12, rem = i & 4095, f = rem >> 5, g = rem & 31;
        float v = (g < GG) ? W1[l * GG * FF + g * FF + f] : 0.f;
        w1t[i] = f2bf(v);
    }
    if (i < 3 * 16384) {
        int l = i >> 14, rem = i & 16383, f = rem >> 7, k = rem & 127;
        w2s[l * 16384 + f * 128 + (k ^ ((f & 7) << 3))] = f2bf(W2[l * 16384 + k * FF + f]);
    }
    if (i < 9 * 16384) {
        int m = i / 49152;
        int rem = i - m * 49152;
        int l = rem >> 14;
        int rk = rem & 16383;
        int f = rk >> 7, k = rk & 127;
        const float* src = (m == 0) ? Win : ((m == 1) ? Wf : Wd);
        float v = src[l * 16384 + k * 128 + f];
        ushort_t h = f2bf(v);
        whi[i] = h;
        wlo[i] = f2bf(v - bf2f(h));
    }
}

// ---- x init ----
__global__ __launch_bounds__(256) void k_init_x(const float* __restrict__ emb,
                                                const int* __restrict__ z,
                                                float* __restrict__ x) {
    int i = blockIdx.x * 256 + threadIdx.x;
    if (i < BB * AA * FF) {
        int row = i >> 7, f = i & 127;
        x[i] = emb[z[row] * FF + f];
    }
}

// ---- fused row-GEMM kernel: G1 ts=ssp(agg@Wf+bf); G2 xn=x+ts@Wd+bd; G3 y=xn@Win ----
// split-bf16 (hi/lo) 3-MFMA GEMMs => ~fp32 accuracy.
// 8 rows/block, 512 thr, wave w owns f-cols [w*16, w*16+16).
// mode: 1 = do G1+G2 (A from agg; writes x, optionally out); 2 = do G3 -> y; 4 = write out
__global__ __launch_bounds__(512) void k_ffn(
    const float* __restrict__ agg, const float* __restrict__ x_in,
    float* __restrict__ x_out, float* __restrict__ y, float* __restrict__ out,
    const ushort_t* __restrict__ wfh, const ushort_t* __restrict__ wfl, const float* __restrict__ bfv_g,
    const ushort_t* __restrict__ wdh, const ushort_t* __restrict__ wdl, const float* __restrict__ bdv_g,
    const ushort_t* __restrict__ wih, const ushort_t* __restrict__ wil,
    int mode) {
    __shared__ ushort_t tsh[8][136];
    __shared__ ushort_t tsl[8][136];
    const int t = threadIdx.x;
    const int lane = t & 63, w = t >> 6;
    const int l15 = lane & 15, l4 = lane >> 4;
    const int r0 = blockIdx.x << 3;
    const int fcol = (w << 4) + l15;

    bf16x8 Ah[4], Al[4];

    // helper: load A-frags (4 ks) from a global fp32 row-major [2048][128] matrix, hi/lo split
    auto loadA_global = [&](const float* __restrict__ M) {
#pragma unroll
        for (int ks = 0; ks < 4; ++ks) {
            float v[8];
            if (l15 < 8) {
                const float4* p = (const float4*)(M + ((size_t)(r0 + l15) << 7) + (ks << 5) + (l4 << 3));
                float4 a = p[0], b = p[1];
                v[0] = a.x; v[1] = a.y; v[2] = a.z; v[3] = a.w;
                v[4] = b.x; v[5] = b.y; v[6] = b.z; v[7] = b.w;
            } else {
#pragma unroll
                for (int j = 0; j < 8; ++j) v[j] = 0.f;
            }
#pragma unroll
            for (int j = 0; j < 8; ++j) {
                ushort_t h = f2bf(v[j]);
                Ah[ks][j] = (short)h;
                Al[ks][j] = (short)f2bf(v[j] - bf2f(h));
            }
        }
    };
    auto loadA_lds = [&]() {
#pragma unroll
        for (int ks = 0; ks < 4; ++ks) {
            if (l15 < 8) {
                const char* base = (const char*)&tsh[l15][0] + (ks << 6) + (l4 << 4);
                Ah[ks] = *(const bf16x8*)base;
                const char* basel = (const char*)&tsl[l15][0] + (ks << 6) + (l4 << 4);
                Al[ks] = *(const bf16x8*)basel;
            } else {
#pragma unroll
                for (int j = 0; j < 8; ++j) { Ah[ks][j] = 0; Al[ks][j] = 0; }
            }
        }
    };

    if (mode & 1) {
        // ---- G1: ts = ssp(agg @ Wf + bf) ----
        loadA_global(agg);
        float bfv = bfv_g[fcol];
        f32x4 acc = {bfv, bfv, bfv, bfv};
#pragma unroll
        for (int ks = 0; ks < 4; ++ks) {
            const bf16x8 Bh = *(const bf16x8*)(wfh + ((size_t)fcol << 7) + (ks << 5) + (l4 << 3));
            const bf16x8 Bl = *(const bf16x8*)(wfl + ((size_t)fcol << 7) + (ks << 5) + (l4 << 3));
            acc = __builtin_amdgcn_mfma_f32_16x16x32_bf16(Al[ks], Bh, acc, 0, 0, 0);
            acc = __builtin_amdgcn_mfma_f32_16x16x32_bf16(Ah[ks], Bl, acc, 0, 0, 0);
            acc = __builtin_amdgcn_mfma_f32_16x16x32_bf16(Ah[ks], Bh, acc, 0, 0, 0);
        }
#pragma unroll
        for (int reg = 0; reg < 4; ++reg) {
            int r = (l4 << 2) + reg;
            if (r < 8) {
                float v = ssp_f(acc[reg]);
                ushort_t h = f2bf(v);
                tsh[r][fcol] = h;
                tsl[r][fcol] = f2bf(v - bf2f(h));
            }
        }
        __syncthreads();
        // ---- G2: xn = x + ts @ Wd + bd ----
        loadA_lds();
        float bdv = bdv_g[fcol];
        f32x4 acc2 = {bdv, bdv, bdv, bdv};
#pragma unroll
        for (int ks = 0; ks < 4; ++ks) {
            const bf16x8 Bh = *(const bf16x8*)(wdh + ((size_t)fcol << 7) + (ks << 5) + (l4 << 3));
            const bf16x8 Bl = *(const bf16x8*)(wdl + ((size_t)fcol << 7) + (ks << 5) + (l4 << 3));
            acc2 = __builtin_amdgcn_mfma_f32_16x16x32_bf16(Al[ks], Bh, acc2, 0, 0, 0);
            acc2 = __builtin_amdgcn_mfma_f32_16x16x32_bf16(Ah[ks], Bl, acc2, 0, 0, 0);
            acc2 = __builtin_amdgcn_mfma_f32_16x16x32_bf16(Ah[ks], Bh, acc2, 0, 0, 0);
        }
        __syncthreads();   // all ts reads done before overwriting planes with xn
#pragma unroll
        for (int reg = 0; reg < 4; ++reg) {
            int r = (l4 << 2) + reg;
            if (r < 8) {
                size_t gi = ((size_t)(r0 + r) << 7) + fcol;
                float xn = x_in[gi] + acc2[reg];
                x_out[gi] = xn;
                if (mode & 4) out[gi] = xn;
                if (mode & 2) {
                    ushort_t h = f2bf(xn);
                    tsh[r][fcol] = h;
                    tsl[r][fcol] = f2bf(xn - bf2f(h));
                }
            }
        }
        if (mode & 2) __syncthreads();
    }
    if (mode & 2) {
        // ---- G3: y = xn @ Win (no bias) ----
        if (mode & 1) loadA_lds(); else loadA_global(x_in);
        f32x4 acc3 = {0.f, 0.f, 0.f, 0.f};
#pragma unroll
        for (int ks = 0; ks < 4; ++ks) {
            const bf16x8 Bh = *(const bf16x8*)(wih + ((size_t)fcol << 7) + (ks << 5) + (l4 << 3));
            const bf16x8 Bl = *(const bf16x8*)(wil + ((size_t)fcol << 7) + (ks << 5) + (l4 << 3));
            acc3 = __builtin_amdgcn_mfma_f32_16x16x32_bf16(Al[ks], Bh, acc3, 0, 0, 0);
            acc3 = __builtin_amdgcn_mfma_f32_16x16x32_bf16(Ah[ks], Bl, acc3, 0, 0, 0);
            acc3 = __builtin_amdgcn_mfma_f32_16x16x32_bf16(Ah[ks], Bh, acc3, 0, 0, 0);
        }
#pragma unroll
        for (int reg = 0; reg < 4; ++reg) {
            int r = (l4 << 2) + reg;
            if (r < 8) y[((size_t)(r0 + r) << 7) + fcol] = acc3[reg];
        }
    }
}

// LDS layout (dynamic, 67072 B):
//  [0,32768)      h bf16 [128n][128f], swizzled: byte = n*256 + ((f*2) ^ ((n&7)<<4))
//  [32768,65536)  W2T bf16 (linear global_load_lds copy of pre-swizzled global image)
//  [0,65536)      (epilogue alias) y fp32 [128][128], elem ^= (n&7)<<2 swizzle
//  [0,4096)       (final alias) red: 8 waves x 128 f32, fl ^ (g<<3) swizzle
//  [65536,66048)  cm f32[128]; [66048,66560) nbr i32[128]; [66560,67072) r f32[128]
#define SMEM_BYTES 67072

__global__ __launch_bounds__(512, 4) void k_cfconv(
    const float* __restrict__ positions, const float* __restrict__ cell,
    const float* __restrict__ cell_offset, const float* __restrict__ nmask,
    const int* __restrict__ neighbors,
    const ushort_t* __restrict__ w1t, const float* __restrict__ b1,
    const ushort_t* __restrict__ w2s, const float* __restrict__ b2,
    const float* __restrict__ y, float* __restrict__ agg) {
    extern __shared__ char smem[];
    float* cm_s = (float*)(smem + 65536);
    int* nbr_s = (int*)(smem + 66048);
    float* r_s = (float*)(smem + 66560);
    float* y_s = (float*)smem;
    float* red_s = (float*)smem;

    const int row = blockIdx.x;
    const int b = row >> 7;
    const int t = threadIdx.x;
    const int lane = t & 63, w = t >> 6;       // 8 waves
    const int l15 = lane & 15, l4 = lane >> 4;

    // -- async W2T global->LDS at entry: 32 x 1KiB blocks, 4 per wave --
    {
        const char* gsrc = (const char*)w2s;
#pragma unroll
        for (int i = 0; i < 4; ++i) {
            int blk = (w << 2) + i;
            GLOBAL_LOAD_LDS16(gsrc + (blk << 10) + (lane << 4), smem + 32768 + (blk << 10));
        }
    }

    // -- phase 0a: distances + cutoff --
    if (t < NNB) {
        int nb = neighbors[row * NNB + t];
        nbr_s[t] = nb;
        float px = positions[row * 3 + 0], py = positions[row * 3 + 1], pz = positions[row * 3 + 2];
        int nrow = b * AA + nb;
        float qx = positions[nrow * 3 + 0], qy = positions[nrow * 3 + 1], qz = positions[nrow * 3 + 2];
        const float* co = cell_offset + (size_t)row * NNB * 3 + (size_t)t * 3;
        const float* cl = cell + b * 9;
        float c0 = co[0], c1 = co[1], c2 = co[2];
        float ox = c0 * cl[0] + c1 * cl[3] + c2 * cl[6];
        float oy = c0 * cl[1] + c1 * cl[4] + c2 * cl[7];
        float oz = c0 * cl[2] + c1 * cl[5] + c2 * cl[8];
        float dx = qx - px + ox, dy = qy - py + oy, dz = qz - pz + oz;
        float d2 = dx * dx + dy * dy + dz * dz;
        float mk = nmask[row * NNB + t];
        float r = (mk > 0.f) ? sqrtf(d2) : 0.f;
        r_s[t] = r;
        float Cc = 0.5f * (__cosf(r * (3.14159265358979323846f / 5.0f)) + 1.f);
        Cc = (r < 5.0f) ? Cc : 0.f;
        cm_s[t] = Cc * mk;
    } else if (t == NNB) {
        cm_s[NNB] = 0.f; nbr_s[NNB] = 0; r_s[NNB] = 1e9f;
    }
    __syncthreads();   // r_s, nbr_s ready

    // -- phase 1: fij computed IN REGISTERS; D[f][n] = W1T * fijT; ssp; b64 swizzled h write --
    {
        const int nrow = (w << 4) + l15;
        const float rv = r_s[nrow];
        const float width = 5.0f / (GG - 1);
        const float coeff = -0.5f / (width * width);
        bf16x8 fb;
#pragma unroll
        for (int j = 0; j < 8; ++j) {
            int g = (l4 << 3) + j;
            float d = rv - g * width;
            float v = (g < GG && nrow < NNB) ? __expf(coeff * d * d) : 0.f;
            fb[j] = (short)f2bf(v);
        }
        const int base = nrow * 256;
        const int sw = (nrow & 7) << 4;
#pragma unroll
        for (int ft = 0; ft < 8; ++ft) {
            bf16x8 aw = *(const bf16x8*)(w1t + ((ft << 4) + l15) * 32 + (l4 << 3));
            const int f0 = (ft << 4) + (l4 << 2);
            f32x4 c0 = *(const f32x4*)(b1 + f0);
            f32x4 d = __builtin_amdgcn_mfma_f32_16x16x32_bf16(aw, fb, c0, 0, 0, 0);
            unsigned long long pk =
                (unsigned long long)pack2bf(ssp_fast(d[0]), ssp_fast(d[1])) |
                ((unsigned long long)pack2bf(ssp_fast(d[2]), ssp_fast(d[3])) << 32);
            *(unsigned long long*)(smem + base + ((f0 << 1) ^ sw)) = pk;
        }
    }
    __syncthreads();   // h ready; vmcnt drained => W2T in LDS

    // -- phase 2: wave grid 2n x 4f (wave = 64n x 32f) => 192KB LDS reads/block --
    const int wr = w >> 2, wc = w & 3;
    f32x4 acc[4][2];
#pragma unroll
    for (int mi = 0; mi < 4; ++mi)
#pragma unroll
        for (int ft = 0; ft < 2; ++ft) {
            float b2v = b2[(wc << 5) + (ft << 4) + l15];
            f32x4 c0 = {b2v, b2v, b2v, b2v};
            acc[mi][ft] = c0;
        }
#pragma unroll
    for (int ks = 0; ks < 4; ++ks) {
        bf16x8 ha[4];
#pragma unroll
        for (int mi = 0; mi < 4; ++mi) {
            int n = (wr << 6) + (mi << 4) + l15;
            ha[mi] = *(const bf16x8*)(smem + n * 256 + ((((ks << 2) + l4) << 4) ^ ((n & 7) << 4)));
        }
        bf16x8 wbv[2];
#pragma unroll
        for (int ft = 0; ft < 2; ++ft) {
            int f = (wc << 5) + (ft << 4) + l15;
            wbv[ft] = *(const bf16x8*)(smem + 32768 + f * 256 + ((((ks << 2) + l4) << 4) ^ ((f & 7) << 4)));
        }
#pragma unroll
        for (int mi = 0; mi < 4; ++mi) {
            acc[mi][0] = __builtin_amdgcn_mfma_f32_16x16x32_bf16(ha[mi], wbv[0], acc[mi][0], 0, 0, 0);
            acc[mi][1] = __builtin_amdgcn_mfma_f32_16x16x32_bf16(ha[mi], wbv[1], acc[mi][1], 0, 0, 0);
        }
    }
    __syncthreads();   // GEMM LDS reads done; safe to overwrite h/W2 with y

    // -- stage y_nbh via global_load_lds: dest linear, source pre-swizzled per lane --
    {
        const int bA = b * AA;
#pragma unroll
        for (int ii = 0; ii < 8; ++ii) {
            int c = t + (ii << 9);               // chunk 0..4095 (16B each)
            int n = c >> 5, sub = c & 31;
            int nb = nbr_s[n];
            int e0 = (sub << 2) ^ ((n & 7) << 2);
            const float* gp = y + (((size_t)(bA + nb)) << 7) + e0;
            GLOBAL_LOAD_LDS16(gp, smem + ((size_t)c << 4));
        }
    }
    __syncthreads();   // vmcnt drained => y_s ready

    // -- epilogue: part[f] += y * (acc * cm), swizzled y reads --
    float part[2] = {0.f, 0.f};
#pragma unroll
    for (int mi = 0; mi < 4; ++mi) {
#pragma unroll
        for (int r = 0; r < 4; ++r) {
            int n = (wr << 6) + (mi << 4) + (l4 << 2) + r;
            if (n < NNB) {
                float cmv = cm_s[n];
                const float* yrow = y_s + (n << 7);
                int sx = (n & 7) << 2;
                part[0] = fmaf(yrow[((wc << 5) + l15) ^ sx], acc[mi][0][r] * cmv, part[0]);
                part[1] = fmaf(yrow[((wc << 5) + 16 + l15) ^ sx], acc[mi][1][r] * cmv, part[1]);
            }
        }
    }
    __syncthreads();   // y reads done; safe to overwrite with red
    {
        int xg = l4 << 3;
        red_s[(w << 7) + (l4 << 5) + (l15 ^ xg)] = part[0];
        red_s[(w << 7) + (l4 << 5) + ((16 + l15) ^ xg)] = part[1];
    }
    __syncthreads();
    if (t < FF) {
        int wcf = t >> 5, fl = t & 31;
        float s = 0.f;
#pragma unroll
        for (int wr2 = 0; wr2 < 2; ++wr2)
#pragma unroll
            for (int g = 0; g < 4; ++g)
                s += red_s[(((wr2 << 2) + wcf) << 7) + (g << 5) + (fl ^ (g << 3))];
        agg[(size_t)row * FF + t] = s;
    }
}

extern "C" void kernel_launch(void* const* d_in, const int* in_sizes, int n_in,
                              void* d_out, int out_size, void* d_ws, size_t ws_size,
                              hipStream_t stream) {
    const float* positions   = (const float*)d_in[0];
    const float* cell        = (const float*)d_in[1];
    const float* cell_offset = (const float*)d_in[2];
    const float* nmask       = (const float*)d_in[3];
    const float* emb         = (const float*)d_in[4];
    const float* filt_W1     = (const float*)d_in[5];
    const float* filt_b1     = (const float*)d_in[6];
    const float* filt_W2     = (const float*)d_in[7];
    const float* filt_b2     = (const float*)d_in[8];
    const float* in2f_W      = (const float*)d_in[9];
    const float* f2out_W     = (const float*)d_in[10];
    const float* f2out_b     = (const float*)d_in[11];
    const float* dense_W     = (const float*)d_in[12];
    const float* dense_b     = (const float*)d_in[13];
    const int* atomic_numbers = (const int*)d_in[14];
    const int* neighbors      = (const int*)d_in[15];
    float* out = (float*)d_out;

    float* x   = (float*)d_ws;                         // 262144 f32
    float* yb  = x + BB * AA * FF;                     // 262144 f32
    float* agg = yb + BB * AA * FF;                    // 262144 f32
    ushort_t* w1t = (ushort_t*)(agg + BB * AA * FF);   // 12288 u16
    ushort_t* w2s = w1t + 3 * 128 * 32;                // 49152 u16
    ushort_t* whi = w2s + 3 * 16384;                   // 147456 u16
    ushort_t* wlo = whi + 9 * 16384;                   // 147456 u16

    k_prep<<<576, 256, 0, stream>>>(filt_W1, filt_W2, in2f_W, f2out_W, dense_W,
                                    w1t, w2s, whi, wlo);
    k_init_x<<<(BB * AA * FF + 255) / 256, 256, 0, stream>>>(emb, atomic_numbers, x);

    // y0 = x @ in2f_W[0]  (G3-only)
    k_ffn<<<256, 512, 0, stream>>>(x, x, x, yb, out,
                                   whi + 3 * 16384, wlo + 3 * 16384, f2out_b,
                                   whi + 6 * 16384, wlo + 6 * 16384, dense_b,
                                   whi + 0 * 16384, wlo + 0 * 16384,
                                   2);
    for (int l = 0; l < 3; ++l) {
        k_cfconv<<<BB * AA, 512, SMEM_BYTES, stream>>>(
            positions, cell, cell_offset, nmask, neighbors,
            w1t + (size_t)l * 128 * 32, filt_b1 + (size_t)l * FF,
            w2s + (size_t)l * 128 * 128, filt_b2 + (size_t)l * FF,
            yb, agg);
        int nextl = (l < 2) ? (l + 1) : 0;
        int mode = 1 | ((l < 2) ? 2 : 0) | ((l == 2) ? 4 : 0);
        k_ffn<<<256, 512, 0, stream>>>(agg, x, x, yb, out,
                                       whi + (3 + l) * 16384, wlo + (3 + l) * 16384, f2out_b + (size_t)l * FF,
                                       whi + (6 + l) * 16384, wlo + (6 + l) * 16384, dense_b + (size_t)l * FF,
                                       whi + nextl * 16384, wlo + nextl * 16384,
                                       mode);
    }
}

// Round 10
// 127.488 us; speedup vs baseline: 6.7585x; 1.2075x over previous
//
#include <hip/hip_runtime.h>
#include <math.h>

#define BB 16
#define AA 128
#define NNB 127
#define FF 128
#define GG 25

typedef __attribute__((ext_vector_type(8))) short bf16x8;
typedef __attribute__((ext_vector_type(4))) float f32x4;
typedef unsigned short ushort_t;

__device__ __forceinline__ float ssp_f(float x) {
    return fmaxf(x, 0.f) + log1pf(__expf(-fabsf(x))) - 0.6931471805599453f;
}

// softplus(x)-ln2 with poly log1p: 1 trans op. |err| <= ~1e-5
__device__ __forceinline__ float ssp_fast(float x) {
    float e = __expf(-fabsf(x));
    float p = fmaf(e, 0.03215845f, -0.13606275f);
    p = fmaf(e, p, 0.28947478f);
    p = fmaf(e, p, -0.49190896f);
    p = fmaf(e, p, 0.99949556f);
    return fmaxf(x, 0.f) + e * p - 0.6931471805599453f;
}

__device__ __forceinline__ ushort_t f2bf(float f) {
    unsigned int u = __float_as_uint(f);
    unsigned int r = (u + 0x7fffu + ((u >> 16) & 1u)) >> 16;
    return (ushort_t)r;
}

__device__ __forceinline__ float bf2f(ushort_t h) {
    return __uint_as_float(((unsigned int)h) << 16);
}

__device__ __forceinline__ unsigned int pack2bf(float lo, float hi) {
    return (unsigned int)f2bf(lo) | ((unsigned int)f2bf(hi) << 16);
}

// ---- prep: W1T bf16; W2 fragment-ordered bf16 (direct MFMA B-frag loads); ffn hi/lo split ----
__global__ __launch_bounds__(256) void k_prep(const float* __restrict__ W1,
                                              const float* __restrict__ W2,
                                              const float* __restrict__ Win,
                                              const float* __restrict__ Wf,
                                              const float* __restrict__ Wd,
                                              ushort_t* __restrict__ w1t,
                                              ushort_t* __restrict__ w2f,
                                              ushort_t* __restrict__ whi,
                                              ushort_t* __restrict__ wlo) {
    int i = blockIdx.x * 256 + threadIdx.x;
    if (i < 3 * 128 * 32) {
        int l = i >> 12, rem = i & 4095, f = rem >> 5, g = rem & 31;
        float v = (g < GG) ? W1[l * GG * FF + g * FF + f] : 0.f;
        w1t[i] = f2bf(v);
    }
    if (i < 3 * 16384) {
        // fragment-ordered: unit u = ((ks*8 + wcft)*64 + lane), 8 bf16 each.
        // lane's fragment: f = (wcft>>1)*32 + (wcft&1)*16 + (lane&15), k = ks*32 + (lane>>4)*8 + j
        int l = i >> 14, e = i & 16383;
        int u = e >> 3, j = e & 7;
        int ks = u >> 9, rem = u & 511;
        int wcft = rem >> 6, lane = rem & 63;
        int f = (wcft >> 1) * 32 + (wcft & 1) * 16 + (lane & 15);
        int k = ks * 32 + (lane >> 4) * 8 + j;
        w2f[i] = f2bf(W2[l * 16384 + k * 128 + f]);
    }
    if (i < 9 * 16384) {
        int m = i / 49152;
        int rem = i - m * 49152;
        int l = rem >> 14;
        int rk = rem & 16383;
        int f = rk >> 7, k = rk & 127;
        const float* src = (m == 0) ? Win : ((m == 1) ? Wf : Wd);
        float v = src[l * 16384 + k * 128 + f];
        ushort_t h = f2bf(v);
        whi[i] = h;
        wlo[i] = f2bf(v - bf2f(h));
    }
}

// ---- x init ----
__global__ __launch_bounds__(256) void k_init_x(const float* __restrict__ emb,
                                                const int* __restrict__ z,
                                                float* __restrict__ x) {
    int i = blockIdx.x * 256 + threadIdx.x;
    if (i < BB * AA * FF) {
        int row = i >> 7, f = i & 127;
        x[i] = emb[z[row] * FF + f];
    }
}

// ---- fused row-GEMM kernel: G1 ts=ssp(agg@Wf+bf); G2 xn=x+ts@Wd+bd; G3 y=xn@Win ----
__global__ __launch_bounds__(512) void k_ffn(
    const float* __restrict__ agg, const float* __restrict__ x_in,
    float* __restrict__ x_out, float* __restrict__ y, float* __restrict__ out,
    const ushort_t* __restrict__ wfh, const ushort_t* __restrict__ wfl, const float* __restrict__ bfv_g,
    const ushort_t* __restrict__ wdh, const ushort_t* __restrict__ wdl, const float* __restrict__ bdv_g,
    const ushort_t* __restrict__ wih, const ushort_t* __restrict__ wil,
    int mode) {
    __shared__ ushort_t tsh[8][136];
    __shared__ ushort_t tsl[8][136];
    const int t = threadIdx.x;
    const int lane = t & 63, w = t >> 6;
    const int l15 = lane & 15, l4 = lane >> 4;
    const int r0 = blockIdx.x << 3;
    const int fcol = (w << 4) + l15;

    bf16x8 Ah[4], Al[4];

    auto loadA_global = [&](const float* __restrict__ M) {
#pragma unroll
        for (int ks = 0; ks < 4; ++ks) {
            float v[8];
            if (l15 < 8) {
                const float4* p = (const float4*)(M + ((size_t)(r0 + l15) << 7) + (ks << 5) + (l4 << 3));
                float4 a = p[0], b = p[1];
                v[0] = a.x; v[1] = a.y; v[2] = a.z; v[3] = a.w;
                v[4] = b.x; v[5] = b.y; v[6] = b.z; v[7] = b.w;
            } else {
#pragma unroll
                for (int j = 0; j < 8; ++j) v[j] = 0.f;
            }
#pragma unroll
            for (int j = 0; j < 8; ++j) {
                ushort_t h = f2bf(v[j]);
                Ah[ks][j] = (short)h;
                Al[ks][j] = (short)f2bf(v[j] - bf2f(h));
            }
        }
    };
    auto loadA_lds = [&]() {
#pragma unroll
        for (int ks = 0; ks < 4; ++ks) {
            if (l15 < 8) {
                const char* base = (const char*)&tsh[l15][0] + (ks << 6) + (l4 << 4);
                Ah[ks] = *(const bf16x8*)base;
                const char* basel = (const char*)&tsl[l15][0] + (ks << 6) + (l4 << 4);
                Al[ks] = *(const bf16x8*)basel;
            } else {
#pragma unroll
                for (int j = 0; j < 8; ++j) { Ah[ks][j] = 0; Al[ks][j] = 0; }
            }
        }
    };

    if (mode & 1) {
        loadA_global(agg);
        float bfv = bfv_g[fcol];
        f32x4 acc = {bfv, bfv, bfv, bfv};
#pragma unroll
        for (int ks = 0; ks < 4; ++ks) {
            const bf16x8 Bh = *(const bf16x8*)(wfh + ((size_t)fcol << 7) + (ks << 5) + (l4 << 3));
            const bf16x8 Bl = *(const bf16x8*)(wfl + ((size_t)fcol << 7) + (ks << 5) + (l4 << 3));
            acc = __builtin_amdgcn_mfma_f32_16x16x32_bf16(Al[ks], Bh, acc, 0, 0, 0);
            acc = __builtin_amdgcn_mfma_f32_16x16x32_bf16(Ah[ks], Bl, acc, 0, 0, 0);
            acc = __builtin_amdgcn_mfma_f32_16x16x32_bf16(Ah[ks], Bh, acc, 0, 0, 0);
        }
#pragma unroll
        for (int reg = 0; reg < 4; ++reg) {
            int r = (l4 << 2) + reg;
            if (r < 8) {
                float v = ssp_f(acc[reg]);
                ushort_t h = f2bf(v);
                tsh[r][fcol] = h;
                tsl[r][fcol] = f2bf(v - bf2f(h));
            }
        }
        __syncthreads();
        loadA_lds();
        float bdv = bdv_g[fcol];
        f32x4 acc2 = {bdv, bdv, bdv, bdv};
#pragma unroll
        for (int ks = 0; ks < 4; ++ks) {
            const bf16x8 Bh = *(const bf16x8*)(wdh + ((size_t)fcol << 7) + (ks << 5) + (l4 << 3));
            const bf16x8 Bl = *(const bf16x8*)(wdl + ((size_t)fcol << 7) + (ks << 5) + (l4 << 3));
            acc2 = __builtin_amdgcn_mfma_f32_16x16x32_bf16(Al[ks], Bh, acc2, 0, 0, 0);
            acc2 = __builtin_amdgcn_mfma_f32_16x16x32_bf16(Ah[ks], Bl, acc2, 0, 0, 0);
            acc2 = __builtin_amdgcn_mfma_f32_16x16x32_bf16(Ah[ks], Bh, acc2, 0, 0, 0);
        }
        __syncthreads();
#pragma unroll
        for (int reg = 0; reg < 4; ++reg) {
            int r = (l4 << 2) + reg;
            if (r < 8) {
                size_t gi = ((size_t)(r0 + r) << 7) + fcol;
                float xn = x_in[gi] + acc2[reg];
                x_out[gi] = xn;
                if (mode & 4) out[gi] = xn;
                if (mode & 2) {
                    ushort_t h = f2bf(xn);
                    tsh[r][fcol] = h;
                    tsl[r][fcol] = f2bf(xn - bf2f(h));
                }
            }
        }
        if (mode & 2) __syncthreads();
    }
    if (mode & 2) {
        if (mode & 1) loadA_lds(); else loadA_global(x_in);
        f32x4 acc3 = {0.f, 0.f, 0.f, 0.f};
#pragma unroll
        for (int ks = 0; ks < 4; ++ks) {
            const bf16x8 Bh = *(const bf16x8*)(wih + ((size_t)fcol << 7) + (ks << 5) + (l4 << 3));
            const bf16x8 Bl = *(const bf16x8*)(wil + ((size_t)fcol << 7) + (ks << 5) + (l4 << 3));
            acc3 = __builtin_amdgcn_mfma_f32_16x16x32_bf16(Al[ks], Bh, acc3, 0, 0, 0);
            acc3 = __builtin_amdgcn_mfma_f32_16x16x32_bf16(Ah[ks], Bl, acc3, 0, 0, 0);
            acc3 = __builtin_amdgcn_mfma_f32_16x16x32_bf16(Ah[ks], Bh, acc3, 0, 0, 0);
        }
#pragma unroll
        for (int reg = 0; reg < 4; ++reg) {
            int r = (l4 << 2) + reg;
            if (r < 8) y[((size_t)(r0 + r) << 7) + fcol] = acc3[reg];
        }
    }
}

// LDS layout (dynamic, 34304 B):
//  [0,32768)      h bf16 [128n][128f], swizzled: byte = n*256 + ((f*2) ^ ((n&7)<<4))
//  [0,4096)       (post-phase2 alias) red: 8 waves x 128 f32, swizzled
//  [32768,33280)  cm f32[128]; [33280,33792) nbr i32[128]; [33792,34304) r f32[128]
#define SMEM_BYTES 34304

__global__ __launch_bounds__(512, 6) void k_cfconv(
    const float* __restrict__ positions, const float* __restrict__ cell,
    const float* __restrict__ cell_offset, const float* __restrict__ nmask,
    const int* __restrict__ neighbors,
    const ushort_t* __restrict__ w1t, const float* __restrict__ b1,
    const ushort_t* __restrict__ w2f, const float* __restrict__ b2,
    const float* __restrict__ y, float* __restrict__ agg) {
    extern __shared__ char smem[];
    float* cm_s = (float*)(smem + 32768);
    int* nbr_s = (int*)(smem + 33280);
    float* r_s = (float*)(smem + 33792);
    float* red_s = (float*)smem;

    const int row = blockIdx.x;
    const int b = row >> 7;
    const int t = threadIdx.x;
    const int lane = t & 63, w = t >> 6;       // 8 waves
    const int l15 = lane & 15, l4 = lane >> 4;
    const int wr = w >> 2, wc = w & 3;

    // -- phase 0a: distances + cutoff --
    if (t < NNB) {
        int nb = neighbors[row * NNB + t];
        nbr_s[t] = nb;
        float px = positions[row * 3 + 0], py = positions[row * 3 + 1], pz = positions[row * 3 + 2];
        int nrow = b * AA + nb;
        float qx = positions[nrow * 3 + 0], qy = positions[nrow * 3 + 1], qz = positions[nrow * 3 + 2];
        const float* co = cell_offset + (size_t)row * NNB * 3 + (size_t)t * 3;
        const float* cl = cell + b * 9;
        float c0 = co[0], c1 = co[1], c2 = co[2];
        float ox = c0 * cl[0] + c1 * cl[3] + c2 * cl[6];
        float oy = c0 * cl[1] + c1 * cl[4] + c2 * cl[7];
        float oz = c0 * cl[2] + c1 * cl[5] + c2 * cl[8];
        float dx = qx - px + ox, dy = qy - py + oy, dz = qz - pz + oz;
        float d2 = dx * dx + dy * dy + dz * dz;
        float mk = nmask[row * NNB + t];
        float r = (mk > 0.f) ? sqrtf(d2) : 0.f;
        r_s[t] = r;
        float Cc = 0.5f * (__cosf(r * (3.14159265358979323846f / 5.0f)) + 1.f);
        Cc = (r < 5.0f) ? Cc : 0.f;
        cm_s[t] = Cc * mk;
    } else if (t == NNB) {
        cm_s[NNB] = 0.f; nbr_s[NNB] = 0; r_s[NNB] = 1e9f;
    }
    __syncthreads();   // (1) r_s, nbr_s ready

    // -- phase 1: fij in registers; D[f][n] = W1T * fijT; ssp; b64 swizzled h write --
    {
        const int nrow = (w << 4) + l15;
        const float rv = r_s[nrow];
        const float width = 5.0f / (GG - 1);
        const float coeff = -0.5f / (width * width);
        bf16x8 fb;
#pragma unroll
        for (int j = 0; j < 8; ++j) {
            int g = (l4 << 3) + j;
            float d = rv - g * width;
            float v = (g < GG && nrow < NNB) ? __expf(coeff * d * d) : 0.f;
            fb[j] = (short)f2bf(v);
        }
        const int base = nrow * 256;
        const int sw = (nrow & 7) << 4;
#pragma unroll
        for (int ft = 0; ft < 8; ++ft) {
            bf16x8 aw = *(const bf16x8*)(w1t + ((ft << 4) + l15) * 32 + (l4 << 3));
            const int f0 = (ft << 4) + (l4 << 2);
            f32x4 c0 = *(const f32x4*)(b1 + f0);
            f32x4 d = __builtin_amdgcn_mfma_f32_16x16x32_bf16(aw, fb, c0, 0, 0, 0);
            unsigned long long pk =
                (unsigned long long)pack2bf(ssp_fast(d[0]), ssp_fast(d[1])) |
                ((unsigned long long)pack2bf(ssp_fast(d[2]), ssp_fast(d[3])) << 32);
            *(unsigned long long*)(smem + base + ((f0 << 1) ^ sw)) = pk;
        }
    }

    // issue first W2 fragment loads before the barrier (independent of LDS)
#define W2LD(ks, ft) (*(const bf16x8*)(w2f + (((((ks) << 3) + (wc << 1) + (ft)) << 6) + lane) * 8))
    bf16x8 wb0 = W2LD(0, 0), wb1 = W2LD(0, 1);
    __syncthreads();   // (2) h ready

    // -- phase 2: wave (wr,wc) = 64n x 32f; B-frags prefetched from global/L2 --
    f32x4 acc[4][2];
#pragma unroll
    for (int mi = 0; mi < 4; ++mi)
#pragma unroll
        for (int ft = 0; ft < 2; ++ft) {
            float b2v = b2[(wc << 5) + (ft << 4) + l15];
            f32x4 c0 = {b2v, b2v, b2v, b2v};
            acc[mi][ft] = c0;
        }
#pragma unroll
    for (int ks = 0; ks < 4; ++ks) {
        bf16x8 wn0, wn1;
        if (ks < 3) { wn0 = W2LD(ks + 1, 0); wn1 = W2LD(ks + 1, 1); }
        bf16x8 ha[4];
#pragma unroll
        for (int mi = 0; mi < 4; ++mi) {
            int n = (wr << 6) + (mi << 4) + l15;
            ha[mi] = *(const bf16x8*)(smem + n * 256 + ((((ks << 2) + l4) << 4) ^ ((n & 7) << 4)));
        }
#pragma unroll
        for (int mi = 0; mi < 4; ++mi) {
            acc[mi][0] = __builtin_amdgcn_mfma_f32_16x16x32_bf16(ha[mi], wb0, acc[mi][0], 0, 0, 0);
            acc[mi][1] = __builtin_amdgcn_mfma_f32_16x16x32_bf16(ha[mi], wb1, acc[mi][1], 0, 0, 0);
        }
        if (ks < 3) { wb0 = wn0; wb1 = wn1; }
    }
#undef W2LD
    __syncthreads();   // (3) all h reads done; red region safe

    // -- epilogue: gather y rows directly from L2; part += y * (acc * cm) --
    float part0 = 0.f, part1 = 0.f;
    const float* ybase = y + ((size_t)(b * AA) << 7) + (wc << 5) + l15;
#pragma unroll
    for (int mi = 0; mi < 4; ++mi) {
        float yv0[4], yv1[4], cmv[4];
#pragma unroll
        for (int r = 0; r < 4; ++r) {
            int n = (wr << 6) + (mi << 4) + (l4 << 2) + r;
            int nb = nbr_s[n];
            cmv[r] = cm_s[n];
            const float* yr = ybase + ((size_t)nb << 7);
            yv0[r] = yr[0];
            yv1[r] = yr[16];
        }
#pragma unroll
        for (int r = 0; r < 4; ++r) {
            part0 = fmaf(yv0[r], acc[mi][0][r] * cmv[r], part0);
            part1 = fmaf(yv1[r], acc[mi][1][r] * cmv[r], part1);
        }
    }
    {
        int xg = l4 << 3;
        red_s[(w << 7) + (l4 << 5) + (l15 ^ xg)] = part0;
        red_s[(w << 7) + (l4 << 5) + ((16 + l15) ^ xg)] = part1;
    }
    __syncthreads();   // (4)
    if (t < FF) {
        int wcf = t >> 5, fl = t & 31;
        float s = 0.f;
#pragma unroll
        for (int wr2 = 0; wr2 < 2; ++wr2)
#pragma unroll
            for (int g = 0; g < 4; ++g)
                s += red_s[(((wr2 << 2) + wcf) << 7) + (g << 5) + (fl ^ (g << 3))];
        agg[(size_t)row * FF + t] = s;
    }
}

extern "C" void kernel_launch(void* const* d_in, const int* in_sizes, int n_in,
                              void* d_out, int out_size, void* d_ws, size_t ws_size,
                              hipStream_t stream) {
    const float* positions   = (const float*)d_in[0];
    const float* cell        = (const float*)d_in[1];
    const float* cell_offset = (const float*)d_in[2];
    const float* nmask       = (const float*)d_in[3];
    const float* emb         = (const float*)d_in[4];
    const float* filt_W1     = (const float*)d_in[5];
    const float* filt_b1     = (const float*)d_in[6];
    const float* filt_W2     = (const float*)d_in[7];
    const float* filt_b2     = (const float*)d_in[8];
    const float* in2f_W      = (const float*)d_in[9];
    const float* f2out_W     = (const float*)d_in[10];
    const float* f2out_b     = (const float*)d_in[11];
    const float* dense_W     = (const float*)d_in[12];
    const float* dense_b     = (const float*)d_in[13];
    const int* atomic_numbers = (const int*)d_in[14];
    const int* neighbors      = (const int*)d_in[15];
    float* out = (float*)d_out;

    float* x   = (float*)d_ws;                         // 262144 f32
    float* yb  = x + BB * AA * FF;                     // 262144 f32
    float* agg = yb + BB * AA * FF;                    // 262144 f32
    ushort_t* w1t = (ushort_t*)(agg + BB * AA * FF);   // 12288 u16
    ushort_t* w2f = w1t + 3 * 128 * 32;                // 49152 u16
    ushort_t* whi = w2f + 3 * 16384;                   // 147456 u16
    ushort_t* wlo = whi + 9 * 16384;                   // 147456 u16

    k_prep<<<576, 256, 0, stream>>>(filt_W1, filt_W2, in2f_W, f2out_W, dense_W,
                                    w1t, w2f, whi, wlo);
    k_init_x<<<(BB * AA * FF + 255) / 256, 256, 0, stream>>>(emb, atomic_numbers, x);

    // y0 = x @ in2f_W[0]  (G3-only)
    k_ffn<<<256, 512, 0, stream>>>(x, x, x, yb, out,
                                   whi + 3 * 16384, wlo + 3 * 16384, f2out_b,
                                   whi + 6 * 16384, wlo + 6 * 16384, dense_b,
                                   whi + 0 * 16384, wlo + 0 * 16384,
                                   2);
    for (int l = 0; l < 3; ++l) {
        k_cfconv<<<BB * AA, 512, SMEM_BYTES, stream>>>(
            positions, cell, cell_offset, nmask, neighbors,
            w1t + (size_t)l * 128 * 32, filt_b1 + (size_t)l * FF,
            w2f + (size_t)l * 16384, filt_b2 + (size_t)l * FF,
            yb, agg);
        int nextl = (l < 2) ? (l + 1) : 0;
        int mode = 1 | ((l < 2) ? 2 : 0) | ((l == 2) ? 4 : 0);
        k_ffn<<<256, 512, 0, stream>>>(agg, x, x, yb, out,
                                       whi + (3 + l) * 16384, wlo + (3 + l) * 16384, f2out_b + (size_t)l * FF,
                                       whi + (6 + l) * 16384, wlo + (6 + l) * 16384, dense_b + (size_t)l * FF,
                                       whi + nextl * 16384, wlo + nextl * 16384,
                                       mode);
    }
}